// Round 1
// baseline (429.221 us; speedup 1.0000x reference)
//
#include <hip/hip_runtime.h>

typedef unsigned short u16;
typedef __attribute__((ext_vector_type(8))) short short8;
typedef __attribute__((ext_vector_type(4))) float f32x4;
typedef __attribute__((ext_vector_type(4))) unsigned int uint4v;

#define AS1 __attribute__((address_space(1)))
#define AS3 __attribute__((address_space(3)))

#define B_  4
#define S_  2048
#define D_  1024
#define H_  16
#define DK_ 64

__device__ __forceinline__ u16 f2bf(float f) {
  union { float f; unsigned u; } v; v.f = f;
  unsigned r = v.u + 0x7fffu + ((v.u >> 16) & 1u);
  return (u16)(r >> 16);
}

__device__ __forceinline__ void gload_lds16(const void* g, void* l) {
  __builtin_amdgcn_global_load_lds((const AS1 void*)g, (AS3 void*)l, 16, 0, 0);
}

// ---------------- fp32 -> bf16 convert (optionally scaled) ----------------
__global__ __launch_bounds__(256) void conv_bf16(const float* __restrict__ in,
                                                 u16* __restrict__ out,
                                                 int n, float scale) {
  int i = (blockIdx.x * 256 + threadIdx.x) * 8;
  if (i >= n) return;
  f32x4 a = *reinterpret_cast<const f32x4*>(in + i);
  f32x4 b = *reinterpret_cast<const f32x4*>(in + i + 4);
  union { u16 u[8]; uint4v v; } r;
#pragma unroll
  for (int j = 0; j < 4; ++j) {
    r.u[j]     = f2bf(a[j] * scale);
    r.u[4 + j] = f2bf(b[j] * scale);
  }
  *reinterpret_cast<uint4v*>(out + i) = r.v;
}

// ---------------- GEMM: C[M,N] = A[M,K] * B[N,K]^T (+bias) ----------------
// 128x128 tile, BK=64, 256 threads (4 waves, 2x2), each wave 64x64 out.
template<int OUTF32>
__global__ __launch_bounds__(256) void gemm_bt(const u16* __restrict__ A,
                                               const u16* __restrict__ B,
                                               u16* __restrict__ Cb,
                                               float* __restrict__ Cf,
                                               const float* __restrict__ bias,
                                               int M, int N, int K) {
  __shared__ __attribute__((aligned(16))) u16 As[128 * 64];
  __shared__ __attribute__((aligned(16))) u16 Bs[128 * 64];

  const int t = threadIdx.x;
  const int l = t & 63;
  const int w = t >> 6;
  const int wr = w >> 1, wc = w & 1;
  const int m0 = blockIdx.y * 128;
  const int n0 = blockIdx.x * 128;

  f32x4 zero = {0.f, 0.f, 0.f, 0.f};
  f32x4 acc[4][4];
#pragma unroll
  for (int i = 0; i < 4; ++i)
#pragma unroll
    for (int j = 0; j < 4; ++j) acc[i][j] = zero;

  for (int k0 = 0; k0 < K; k0 += 64) {
    __syncthreads();
    // stage A,B tiles: 128 rows x 64 bf16 (128B rows = 8 chunks of 16B)
    // LDS dest linear; global source chunk-swizzled: phys chunk c holds
    // logical chunk c ^ (row&7).
#pragma unroll
    for (int i = 0; i < 4; ++i) {
      int slot = i * 256 + t;
      int r = slot >> 3, c = slot & 7;
      const u16* srcA = A + (size_t)(m0 + r) * K + k0 + ((c ^ (r & 7)) * 8);
      gload_lds16(srcA, (char*)As + (size_t)(i * 256 + w * 64) * 16);
      const u16* srcB = B + (size_t)(n0 + r) * K + k0 + ((c ^ (r & 7)) * 8);
      gload_lds16(srcB, (char*)Bs + (size_t)(i * 256 + w * 64) * 16);
    }
    __syncthreads();

#pragma unroll
    for (int kc = 0; kc < 2; ++kc) {
      short8 a[4], bf[4];
      int lc = kc * 4 + (l >> 4);
#pragma unroll
      for (int i = 0; i < 4; ++i) {
        int ra = wr * 64 + i * 16 + (l & 15);
        a[i] = *reinterpret_cast<const short8*>(&As[ra * 64 + ((lc ^ (ra & 7)) * 8)]);
        int rb = wc * 64 + i * 16 + (l & 15);
        bf[i] = *reinterpret_cast<const short8*>(&Bs[rb * 64 + ((lc ^ (rb & 7)) * 8)]);
      }
#pragma unroll
      for (int mi = 0; mi < 4; ++mi)
#pragma unroll
        for (int ni = 0; ni < 4; ++ni)
          acc[mi][ni] = __builtin_amdgcn_mfma_f32_16x16x32_bf16(a[mi], bf[ni], acc[mi][ni], 0, 0, 0);
    }
  }

  // epilogue: C layout col = l&15, row = (l>>4)*4 + r
#pragma unroll
  for (int ni = 0; ni < 4; ++ni) {
    int col = n0 + wc * 64 + ni * 16 + (l & 15);
    float bv = OUTF32 ? bias[col] : 0.f;
#pragma unroll
    for (int mi = 0; mi < 4; ++mi) {
#pragma unroll
      for (int r = 0; r < 4; ++r) {
        int row = m0 + wr * 64 + mi * 16 + (l >> 4) * 4 + r;
        float v = acc[mi][ni][r];
        if (OUTF32) Cf[(size_t)row * N + col] = v + bv;
        else        Cb[(size_t)row * N + col] = f2bf(v);
      }
    }
  }
}

// ---------------- causal flash attention ----------------
// grid (S/64, B*H); block 256 = 4 waves; wave w owns q rows [q0+16w, q0+16w+16)
__global__ __launch_bounds__(256) void attn_fwd(const u16* __restrict__ Q,
                                                const u16* __restrict__ K,
                                                const u16* __restrict__ V,
                                                u16* __restrict__ AO) {
  __shared__ __attribute__((aligned(16))) u16 Ks[64 * 64];  // [key][d], swizzled
  __shared__ __attribute__((aligned(16))) u16 Vt[64 * 64];  // [d][key], swizzled
  __shared__ __attribute__((aligned(16))) u16 Pl[4 * 16 * 72]; // per-wave P, pad 72

  const int t = threadIdx.x;
  const int l = t & 63;
  const int w = t >> 6;
  const int q0 = blockIdx.x * 64;
  const int bh = blockIdx.y;
  const int b = bh >> 4, h = bh & 15;
  const int qw = q0 + w * 16;
  const size_t base = (size_t)(b * S_) * D_ + h * DK_;

  // Q fragments (Q is pre-scaled by 1/8 via w_q conversion)
  const int qrow = qw + (l & 15);
  short8 qf[2];
#pragma unroll
  for (int kc = 0; kc < 2; ++kc)
    qf[kc] = *reinterpret_cast<const short8*>(Q + base + (size_t)qrow * D_ + kc * 32 + ((l >> 4) * 8));

  f32x4 zero = {0.f, 0.f, 0.f, 0.f};
  f32x4 o[4];
  float m_r[4], l_r[4];
#pragma unroll
  for (int r = 0; r < 4; ++r) { o[r] = zero; m_r[r] = -INFINITY; l_r[r] = 0.f; }

  const int ntiles = blockIdx.x + 1;
  for (int it = 0; it < ntiles; ++it) {
    const int j0 = it * 64;
    __syncthreads();
    // stage K tile [64 keys][64 d] via global_load_lds, source-swizzled
#pragma unroll
    for (int i = 0; i < 2; ++i) {
      int slot = i * 256 + t;
      int r = slot >> 3, c = slot & 7;
      const u16* src = K + base + (size_t)(j0 + r) * D_ + ((c ^ (r & 7)) * 8);
      gload_lds16(src, (char*)Ks + (size_t)(i * 256 + w * 64) * 16);
    }
    // stage V transposed: Vt[d][key], chunk-swizzled by (d&7)
#pragma unroll
    for (int i = 0; i < 2; ++i) {
      int slot = i * 256 + t;
      int r = slot >> 3, c0 = (slot & 7) * 8;
      union { uint4v v; u16 u[8]; } vv;
      vv.v = *reinterpret_cast<const uint4v*>(V + base + (size_t)(j0 + r) * D_ + c0);
#pragma unroll
      for (int j = 0; j < 8; ++j) {
        int d = c0 + j;
        Vt[d * 64 + (((r >> 3) ^ (d & 7)) * 8) + (r & 7)] = vv.u[j];
      }
    }
    __syncthreads();

    if (j0 <= qw + 15) {
      // S = Q K^T  (16 q rows x 64 keys per wave)
      f32x4 s[4];
#pragma unroll
      for (int fk = 0; fk < 4; ++fk) s[fk] = zero;
#pragma unroll
      for (int kc = 0; kc < 2; ++kc) {
        int lc = kc * 4 + (l >> 4);
#pragma unroll
        for (int fk = 0; fk < 4; ++fk) {
          int key = fk * 16 + (l & 15);
          short8 kf = *reinterpret_cast<const short8*>(&Ks[key * 64 + ((lc ^ (key & 7)) * 8)]);
          s[fk] = __builtin_amdgcn_mfma_f32_16x16x32_bf16(qf[kc], kf, s[fk], 0, 0, 0);
        }
      }
      // causal mask (only diagonal-crossing tiles)
      const bool needmask = (j0 + 63 > qw);
      if (needmask) {
#pragma unroll
        for (int fk = 0; fk < 4; ++fk) {
          int key = j0 + fk * 16 + (l & 15);
#pragma unroll
          for (int r = 0; r < 4; ++r) {
            int qi = qw + (l >> 4) * 4 + r;
            if (key > qi) s[fk][r] = -INFINITY;
          }
        }
      }
      // online softmax
      float mnew[4], rr[4];
#pragma unroll
      for (int r = 0; r < 4; ++r) {
        float mx = fmaxf(fmaxf(s[0][r], s[1][r]), fmaxf(s[2][r], s[3][r]));
        mx = fmaxf(mx, __shfl_xor(mx, 1));
        mx = fmaxf(mx, __shfl_xor(mx, 2));
        mx = fmaxf(mx, __shfl_xor(mx, 4));
        mx = fmaxf(mx, __shfl_xor(mx, 8));
        mnew[r] = fmaxf(m_r[r], mx);
        rr[r] = __expf(m_r[r] - mnew[r]);  // exp(-inf - finite) = 0 on first tile
      }
#pragma unroll
      for (int r = 0; r < 4; ++r) {
        float sum = 0.f;
#pragma unroll
        for (int fk = 0; fk < 4; ++fk) {
          float p = __expf(s[fk][r] - mnew[r]);
          s[fk][r] = p;
          sum += p;
        }
        sum += __shfl_xor(sum, 1);
        sum += __shfl_xor(sum, 2);
        sum += __shfl_xor(sum, 4);
        sum += __shfl_xor(sum, 8);
        l_r[r] = l_r[r] * rr[r] + sum;
        m_r[r] = mnew[r];
      }
      // rescale O
#pragma unroll
      for (int fn = 0; fn < 4; ++fn)
#pragma unroll
        for (int r = 0; r < 4; ++r) o[fn][r] *= rr[r];
      // P -> LDS (per-wave private), re-read as A fragments
#pragma unroll
      for (int fk = 0; fk < 4; ++fk)
#pragma unroll
        for (int r = 0; r < 4; ++r)
          Pl[w * 1152 + ((l >> 4) * 4 + r) * 72 + fk * 16 + (l & 15)] = f2bf(s[fk][r]);
      short8 ap[2];
#pragma unroll
      for (int kc = 0; kc < 2; ++kc)
        ap[kc] = *reinterpret_cast<const short8*>(&Pl[w * 1152 + (l & 15) * 72 + kc * 32 + ((l >> 4) * 8)]);
      // O += P V
#pragma unroll
      for (int kc = 0; kc < 2; ++kc) {
        int lc = kc * 4 + (l >> 4);
#pragma unroll
        for (int fn = 0; fn < 4; ++fn) {
          int d = fn * 16 + (l & 15);
          short8 vf = *reinterpret_cast<const short8*>(&Vt[d * 64 + ((lc ^ (d & 7)) * 8)]);
          o[fn] = __builtin_amdgcn_mfma_f32_16x16x32_bf16(ap[kc], vf, o[fn], 0, 0, 0);
        }
      }
    }
  }

  // epilogue: normalize and store bf16
#pragma unroll
  for (int fn = 0; fn < 4; ++fn) {
#pragma unroll
    for (int r = 0; r < 4; ++r) {
      int qi = qw + (l >> 4) * 4 + r;
      float val = o[fn][r] / l_r[r];
      AO[base + (size_t)qi * D_ + fn * 16 + (l & 15)] = f2bf(val);
    }
  }
}

// ---------------- launch ----------------
extern "C" void kernel_launch(void* const* d_in, const int* in_sizes, int n_in,
                              void* d_out, int out_size, void* d_ws, size_t ws_size,
                              hipStream_t stream) {
  const float* x  = (const float*)d_in[0];
  const float* wq = (const float*)d_in[1];
  const float* wk = (const float*)d_in[2];
  const float* wv = (const float*)d_in[3];
  const float* wo = (const float*)d_in[4];
  const float* bo = (const float*)d_in[5];
  float* out = (float*)d_out;

  char* ws = (char*)d_ws;
  u16* XB  = (u16*)(ws);                       // 16 MiB
  u16* WQB = (u16*)(ws + (size_t)(16 << 20));  // 2 MiB each
  u16* WKB = (u16*)(ws + (size_t)(18 << 20));
  u16* WVB = (u16*)(ws + (size_t)(20 << 20));
  u16* WOB = (u16*)(ws + (size_t)(22 << 20));
  u16* Qb  = (u16*)(ws + (size_t)(24 << 20));  // 16 MiB each
  u16* Kb  = (u16*)(ws + (size_t)(40 << 20));
  u16* Vb  = (u16*)(ws + (size_t)(56 << 20));
  u16* AO  = (u16*)(ws + (size_t)(72 << 20));  // ends at 88 MiB

  const int nx = B_ * S_ * D_;   // 8388608
  const int nw = D_ * D_;        // 1048576

  conv_bf16<<<nx / 2048, 256, 0, stream>>>(x, XB, nx, 1.0f);
  conv_bf16<<<nw / 2048, 256, 0, stream>>>(wq, WQB, nw, 0.125f); // fold DK^-0.5
  conv_bf16<<<nw / 2048, 256, 0, stream>>>(wk, WKB, nw, 1.0f);
  conv_bf16<<<nw / 2048, 256, 0, stream>>>(wv, WVB, nw, 1.0f);
  conv_bf16<<<nw / 2048, 256, 0, stream>>>(wo, WOB, nw, 1.0f);

  dim3 g(D_ / 128, (B_ * S_) / 128);  // (8, 64)
  gemm_bt<0><<<g, 256, 0, stream>>>(XB, WQB, Qb, nullptr, nullptr, B_ * S_, D_, D_);
  gemm_bt<0><<<g, 256, 0, stream>>>(XB, WKB, Kb, nullptr, nullptr, B_ * S_, D_, D_);
  gemm_bt<0><<<g, 256, 0, stream>>>(XB, WVB, Vb, nullptr, nullptr, B_ * S_, D_, D_);

  attn_fwd<<<dim3(S_ / 64, B_ * H_), 256, 0, stream>>>(Qb, Kb, Vb, AO);

  gemm_bt<1><<<g, 256, 0, stream>>>(AO, WOB, nullptr, out, bo, B_ * S_, D_, D_);
}

// Round 2
// 334.108 us; speedup vs baseline: 1.2847x; 1.2847x over previous
//
#include <hip/hip_runtime.h>

typedef unsigned short u16;
typedef __attribute__((ext_vector_type(4))) u16 u16x4;
typedef __attribute__((ext_vector_type(8))) short short8;
typedef __attribute__((ext_vector_type(4))) float f32x4;
typedef __attribute__((ext_vector_type(4))) unsigned int uint4v;

#define AS1 __attribute__((address_space(1)))
#define AS3 __attribute__((address_space(3)))

#define B_  4
#define S_  2048
#define D_  1024
#define H_  16
#define DK_ 64

__device__ __forceinline__ u16 f2bf(float f) {
  union { float f; unsigned u; } v; v.f = f;
  unsigned r = v.u + 0x7fffu + ((v.u >> 16) & 1u);
  return (u16)(r >> 16);
}

__device__ __forceinline__ void gload_lds16(const void* g, void* l) {
  __builtin_amdgcn_global_load_lds((const AS1 void*)g, (AS3 void*)l, 16, 0, 0);
}

// ---------------- fp32 -> bf16 convert (optionally scaled) ----------------
__global__ __launch_bounds__(256) void conv_bf16(const float* __restrict__ in,
                                                 u16* __restrict__ out,
                                                 int n, float scale) {
  int i = (blockIdx.x * 256 + threadIdx.x) * 8;
  if (i >= n) return;
  f32x4 a = *reinterpret_cast<const f32x4*>(in + i);
  f32x4 b = *reinterpret_cast<const f32x4*>(in + i + 4);
  union { u16 u[8]; uint4v v; } r;
#pragma unroll
  for (int j = 0; j < 4; ++j) {
    r.u[j]     = f2bf(a[j] * scale);
    r.u[4 + j] = f2bf(b[j] * scale);
  }
  *reinterpret_cast<uint4v*>(out + i) = r.v;
}

// ---------------- GEMM: C[M,N] = A[M,K] * B[N,K]^T ----------------
// MODE 0: QKV fused — cols [0,1024) -> Qb bf16, [1024,2048) -> Kb bf16,
//         [2048,3072) -> Vt bf16 TRANSPOSED per-head ([bh*64+d][s]).
// MODE 1: f32 out + bias (output projection).
template<int MODE>
__global__ __launch_bounds__(256) void gemm_bt(const u16* __restrict__ A,
                                               const u16* __restrict__ B,
                                               u16* __restrict__ Qb,
                                               u16* __restrict__ Kb,
                                               u16* __restrict__ Vt,
                                               float* __restrict__ Cf,
                                               const float* __restrict__ bias,
                                               int M, int N, int K) {
  __shared__ __attribute__((aligned(16))) u16 As[128 * 64];
  __shared__ __attribute__((aligned(16))) u16 Bs[128 * 64];

  const int t = threadIdx.x;
  const int l = t & 63;
  const int w = t >> 6;
  const int wr = w >> 1, wc = w & 1;
  const int m0 = blockIdx.y * 128;
  const int n0 = blockIdx.x * 128;

  f32x4 zero = {0.f, 0.f, 0.f, 0.f};
  f32x4 acc[4][4];
#pragma unroll
  for (int i = 0; i < 4; ++i)
#pragma unroll
    for (int j = 0; j < 4; ++j) acc[i][j] = zero;

  for (int k0 = 0; k0 < K; k0 += 64) {
    __syncthreads();
#pragma unroll
    for (int i = 0; i < 4; ++i) {
      int slot = i * 256 + t;
      int r = slot >> 3, c = slot & 7;
      const u16* srcA = A + (size_t)(m0 + r) * K + k0 + ((c ^ (r & 7)) * 8);
      gload_lds16(srcA, (char*)As + (size_t)(i * 256 + w * 64) * 16);
      const u16* srcB = B + (size_t)(n0 + r) * K + k0 + ((c ^ (r & 7)) * 8);
      gload_lds16(srcB, (char*)Bs + (size_t)(i * 256 + w * 64) * 16);
    }
    __syncthreads();

#pragma unroll
    for (int kc = 0; kc < 2; ++kc) {
      short8 a[4], bf[4];
      int lc = kc * 4 + (l >> 4);
#pragma unroll
      for (int i = 0; i < 4; ++i) {
        int ra = wr * 64 + i * 16 + (l & 15);
        a[i] = *reinterpret_cast<const short8*>(&As[ra * 64 + ((lc ^ (ra & 7)) * 8)]);
        int rb = wc * 64 + i * 16 + (l & 15);
        bf[i] = *reinterpret_cast<const short8*>(&Bs[rb * 64 + ((lc ^ (rb & 7)) * 8)]);
      }
#pragma unroll
      for (int mi = 0; mi < 4; ++mi)
#pragma unroll
        for (int ni = 0; ni < 4; ++ni)
          acc[mi][ni] = __builtin_amdgcn_mfma_f32_16x16x32_bf16(a[mi], bf[ni], acc[mi][ni], 0, 0, 0);
    }
  }

  // epilogue: C layout col = l&15, row = (l>>4)*4 + r
#pragma unroll
  for (int ni = 0; ni < 4; ++ni) {
    int col = n0 + wc * 64 + ni * 16 + (l & 15);
    float bv = (MODE == 1) ? bias[col] : 0.f;
#pragma unroll
    for (int mi = 0; mi < 4; ++mi) {
      int row0 = m0 + wr * 64 + mi * 16 + (l >> 4) * 4;
      if (MODE == 1) {
#pragma unroll
        for (int r = 0; r < 4; ++r)
          Cf[(size_t)(row0 + r) * N + col] = acc[mi][ni][r] + bv;
      } else {
        if (col < 2048) {
          u16* dst = (col < 1024) ? Qb : Kb;
          int c = col & 1023;
#pragma unroll
          for (int r = 0; r < 4; ++r)
            dst[(size_t)(row0 + r) * 1024 + c] = f2bf(acc[mi][ni][r]);
        } else {
          int vc = col - 2048;
          int bh = (row0 >> 11) * 16 + (vc >> 6);
          int s0 = row0 & 2047;
          u16x4 pk;
#pragma unroll
          for (int r = 0; r < 4; ++r) pk[r] = f2bf(acc[mi][ni][r]);
          *reinterpret_cast<u16x4*>(Vt + ((size_t)(bh * 64 + (vc & 63))) * 2048 + s0) = pk;
        }
      }
    }
  }
}

// ---------------- causal flash attention ----------------
// grid (S/128, B*H); block 256 = 4 waves; wave w owns 32 q rows.
// K staged [key][d] swizzled; V^T staged [d][key] swizzled (from global V^T).
__global__ __launch_bounds__(256) void attn_fwd(const u16* __restrict__ Q,
                                                const u16* __restrict__ K,
                                                const u16* __restrict__ Vtg,
                                                u16* __restrict__ AO) {
  __shared__ __attribute__((aligned(16))) u16 Ks[2][64 * 64];
  __shared__ __attribute__((aligned(16))) u16 Vs[2][64 * 64];
  __shared__ __attribute__((aligned(16))) u16 Pl[4][32 * 64];  // per-wave P, XOR-swz

  const int t = threadIdx.x;
  const int l = t & 63;
  const int w = t >> 6;
  const int q0 = blockIdx.x * 128;
  const int bh = blockIdx.y;
  const size_t qkbase = (size_t)((bh >> 4) * S_) * D_ + (bh & 15) * DK_;
  const u16* Vg = Vtg + (size_t)bh * 64 * S_;
  const int qw = q0 + w * 32;

  // Q fragments (pre-scaled by 1/8 via w_q conversion)
  short8 qf[2][2];
#pragma unroll
  for (int mi = 0; mi < 2; ++mi)
#pragma unroll
    for (int kc = 0; kc < 2; ++kc)
      qf[mi][kc] = *reinterpret_cast<const short8*>(
          Q + qkbase + (size_t)(qw + mi * 16 + (l & 15)) * D_ + kc * 32 + ((l >> 4) * 8));

  f32x4 zero = {0.f, 0.f, 0.f, 0.f};
  f32x4 o[2][4];
  float m_r[2][4], l_r[2][4];
#pragma unroll
  for (int mi = 0; mi < 2; ++mi)
#pragma unroll
    for (int r = 0; r < 4; ++r) { o[mi][0] = zero; o[mi][1] = zero; o[mi][2] = zero; o[mi][3] = zero;
                                  m_r[mi][r] = -INFINITY; l_r[mi][r] = 0.f; }

  const int nt = 2 * (blockIdx.x + 1);

  // stage tile 0 into buf 0
  {
    const int j0 = 0;
#pragma unroll
    for (int i = 0; i < 2; ++i) {
      int slot = i * 256 + t;
      int r = slot >> 3, c = t & 7;
      gload_lds16(K + qkbase + (size_t)(j0 + r) * D_ + ((c ^ (r & 7)) * 8),
                  (char*)Ks[0] + (size_t)(i * 256 + w * 64) * 16);
      gload_lds16(Vg + (size_t)r * S_ + j0 + ((c ^ (r & 7)) * 8),
                  (char*)Vs[0] + (size_t)(i * 256 + w * 64) * 16);
    }
  }
  __syncthreads();

  for (int it = 0; it < nt; ++it) {
    const int cur = it & 1;
    const int j0 = it * 64;
    if (it + 1 < nt) {  // prefetch next tile into other buffer
      const int jn = j0 + 64;
#pragma unroll
      for (int i = 0; i < 2; ++i) {
        int slot = i * 256 + t;
        int r = slot >> 3, c = t & 7;
        gload_lds16(K + qkbase + (size_t)(jn + r) * D_ + ((c ^ (r & 7)) * 8),
                    (char*)Ks[cur ^ 1] + (size_t)(i * 256 + w * 64) * 16);
        gload_lds16(Vg + (size_t)r * S_ + jn + ((c ^ (r & 7)) * 8),
                    (char*)Vs[cur ^ 1] + (size_t)(i * 256 + w * 64) * 16);
      }
    }

    if (j0 <= qw + 31) {
      // S = Q K^T  (32 q rows x 64 keys per wave)
      f32x4 s[2][4];
#pragma unroll
      for (int mi = 0; mi < 2; ++mi)
#pragma unroll
        for (int fk = 0; fk < 4; ++fk) s[mi][fk] = zero;
#pragma unroll
      for (int kc = 0; kc < 2; ++kc) {
        int lc = kc * 4 + (l >> 4);
#pragma unroll
        for (int fk = 0; fk < 4; ++fk) {
          int key = fk * 16 + (l & 15);
          short8 kf = *reinterpret_cast<const short8*>(&Ks[cur][key * 64 + ((lc ^ (key & 7)) * 8)]);
          s[0][fk] = __builtin_amdgcn_mfma_f32_16x16x32_bf16(qf[0][kc], kf, s[0][fk], 0, 0, 0);
          s[1][fk] = __builtin_amdgcn_mfma_f32_16x16x32_bf16(qf[1][kc], kf, s[1][fk], 0, 0, 0);
        }
      }
      // causal mask (diagonal-crossing tiles only)
      if (j0 + 63 > qw) {
#pragma unroll
        for (int mi = 0; mi < 2; ++mi)
#pragma unroll
          for (int fk = 0; fk < 4; ++fk) {
            int key = j0 + fk * 16 + (l & 15);
#pragma unroll
            for (int r = 0; r < 4; ++r) {
              int qi = qw + mi * 16 + (l >> 4) * 4 + r;
              if (key > qi) s[mi][fk][r] = -INFINITY;
            }
          }
      }
      // online softmax (keys live in l&15 across the 16-lane group)
#pragma unroll
      for (int mi = 0; mi < 2; ++mi) {
        float rr[4];
#pragma unroll
        for (int r = 0; r < 4; ++r) {
          float mx = fmaxf(fmaxf(s[mi][0][r], s[mi][1][r]), fmaxf(s[mi][2][r], s[mi][3][r]));
          mx = fmaxf(mx, __shfl_xor(mx, 1));
          mx = fmaxf(mx, __shfl_xor(mx, 2));
          mx = fmaxf(mx, __shfl_xor(mx, 4));
          mx = fmaxf(mx, __shfl_xor(mx, 8));
          float mnew = fmaxf(m_r[mi][r], mx);
          rr[r] = __expf(m_r[mi][r] - mnew);
          m_r[mi][r] = mnew;
          float sum = 0.f;
#pragma unroll
          for (int fk = 0; fk < 4; ++fk) {
            float p = __expf(s[mi][fk][r] - mnew);
            s[mi][fk][r] = p;
            sum += p;
          }
          sum += __shfl_xor(sum, 1);
          sum += __shfl_xor(sum, 2);
          sum += __shfl_xor(sum, 4);
          sum += __shfl_xor(sum, 8);
          l_r[mi][r] = l_r[mi][r] * rr[r] + sum;
        }
#pragma unroll
        for (int fn = 0; fn < 4; ++fn)
#pragma unroll
          for (int r = 0; r < 4; ++r) o[mi][fn][r] *= rr[r];
      }
      // P -> per-wave LDS (XOR chunk-swizzled by q&7), re-read as A frags
#pragma unroll
      for (int mi = 0; mi < 2; ++mi)
#pragma unroll
        for (int fk = 0; fk < 4; ++fk) {
          int kch = fk * 2 + ((l & 15) >> 3);
#pragma unroll
          for (int r = 0; r < 4; ++r) {
            int q = mi * 16 + (l >> 4) * 4 + r;
            Pl[w][q * 64 + ((kch ^ (q & 7)) * 8) + (l & 7)] = f2bf(s[mi][fk][r]);
          }
        }
      short8 ap[2][2];
#pragma unroll
      for (int mi = 0; mi < 2; ++mi)
#pragma unroll
        for (int kc = 0; kc < 2; ++kc) {
          int q = mi * 16 + (l & 15);
          int kch = kc * 4 + (l >> 4);
          ap[mi][kc] = *reinterpret_cast<const short8*>(&Pl[w][q * 64 + ((kch ^ (q & 7)) * 8)]);
        }
      // O += P V
#pragma unroll
      for (int kc = 0; kc < 2; ++kc) {
        int lc = kc * 4 + (l >> 4);
#pragma unroll
        for (int fn = 0; fn < 4; ++fn) {
          int d = fn * 16 + (l & 15);
          short8 vf = *reinterpret_cast<const short8*>(&Vs[cur][d * 64 + ((lc ^ (d & 7)) * 8)]);
          o[0][fn] = __builtin_amdgcn_mfma_f32_16x16x32_bf16(ap[0][kc], vf, o[0][fn], 0, 0, 0);
          o[1][fn] = __builtin_amdgcn_mfma_f32_16x16x32_bf16(ap[1][kc], vf, o[1][fn], 0, 0, 0);
        }
      }
    }
    __syncthreads();
  }

  // epilogue: normalize, store bf16
#pragma unroll
  for (int mi = 0; mi < 2; ++mi)
#pragma unroll
    for (int fn = 0; fn < 4; ++fn)
#pragma unroll
      for (int r = 0; r < 4; ++r) {
        int qi = qw + mi * 16 + (l >> 4) * 4 + r;
        float val = o[mi][fn][r] / l_r[mi][r];
        AO[qkbase + (size_t)qi * D_ + fn * 16 + (l & 15)] = f2bf(val);
      }
}

// ---------------- launch ----------------
extern "C" void kernel_launch(void* const* d_in, const int* in_sizes, int n_in,
                              void* d_out, int out_size, void* d_ws, size_t ws_size,
                              hipStream_t stream) {
  const float* x  = (const float*)d_in[0];
  const float* wq = (const float*)d_in[1];
  const float* wk = (const float*)d_in[2];
  const float* wv = (const float*)d_in[3];
  const float* wo = (const float*)d_in[4];
  const float* bo = (const float*)d_in[5];
  float* out = (float*)d_out;

  char* ws = (char*)d_ws;
  u16* XB   = (u16*)(ws);                       // 16 MiB
  u16* WQKV = (u16*)(ws + (size_t)(16 << 20));  // 6 MiB (wq|wk|wv rows)
  u16* WOB  = (u16*)(ws + (size_t)(22 << 20));  // 2 MiB
  u16* Qb   = (u16*)(ws + (size_t)(24 << 20));  // 16 MiB
  u16* Kb   = (u16*)(ws + (size_t)(40 << 20));  // 16 MiB
  u16* Vt   = (u16*)(ws + (size_t)(56 << 20));  // 16 MiB ([bh*64+d][s])
  u16* AO   = (u16*)(ws + (size_t)(72 << 20));  // 16 MiB

  const int nx = B_ * S_ * D_;   // 8388608
  const int nw = D_ * D_;        // 1048576

  conv_bf16<<<nx / 2048, 256, 0, stream>>>(x, XB, nx, 1.0f);
  conv_bf16<<<nw / 2048, 256, 0, stream>>>(wq, WQKV, nw, 0.125f);  // fold DK^-0.5
  conv_bf16<<<nw / 2048, 256, 0, stream>>>(wk, WQKV + nw, nw, 1.0f);
  conv_bf16<<<nw / 2048, 256, 0, stream>>>(wv, WQKV + 2 * nw, nw, 1.0f);
  conv_bf16<<<nw / 2048, 256, 0, stream>>>(wo, WOB, nw, 1.0f);

  // fused QKV projection: M=8192, N=3072, K=1024
  gemm_bt<0><<<dim3(3072 / 128, (B_ * S_) / 128), 256, 0, stream>>>(
      XB, WQKV, Qb, Kb, Vt, nullptr, nullptr, B_ * S_, 3072, D_);

  attn_fwd<<<dim3(S_ / 128, B_ * H_), 256, 0, stream>>>(Qb, Kb, Vt, AO);

  gemm_bt<1><<<dim3(D_ / 128, (B_ * S_) / 128), 256, 0, stream>>>(
      AO, WOB, nullptr, nullptr, nullptr, out, bo, B_ * S_, D_, D_);
}

// Round 3
// 253.028 us; speedup vs baseline: 1.6963x; 1.3204x over previous
//
#include <hip/hip_runtime.h>

typedef unsigned short u16;
typedef unsigned int u32;
typedef __attribute__((ext_vector_type(4))) u16 u16x4;
typedef __attribute__((ext_vector_type(8))) short short8;
typedef __attribute__((ext_vector_type(4))) float f32x4;
typedef __attribute__((ext_vector_type(16))) float f32x16;
typedef __attribute__((ext_vector_type(4))) u32 uint4v;

#define AS1 __attribute__((address_space(1)))
#define AS3 __attribute__((address_space(3)))

#define B_  4
#define S_  2048
#define D_  1024
#define H_  16
#define DK_ 64

__device__ __forceinline__ u16 f2bf(float f) {
  union { float f; unsigned u; } v; v.f = f;
  unsigned r = v.u + 0x7fffu + ((v.u >> 16) & 1u);
  return (u16)(r >> 16);
}

__device__ __forceinline__ u32 cvt_pk_bf16(float lo, float hi) {
  u32 r;
  asm("v_cvt_pk_bf16_f32 %0, %1, %2" : "=v"(r) : "v"(lo), "v"(hi));
  return r;
}

__device__ __forceinline__ void pl32_swap(u32& a, u32& b) {
  asm("v_permlane32_swap_b32 %0, %1" : "+v"(a), "+v"(b));
}

__device__ __forceinline__ void gload_lds16(const void* g, void* l) {
  __builtin_amdgcn_global_load_lds((const AS1 void*)g, (AS3 void*)l, 16, 0, 0);
}

// ---------------- fp32 -> bf16 convert ----------------
__global__ __launch_bounds__(256) void conv_bf16(const float* __restrict__ in,
                                                 u16* __restrict__ out,
                                                 int n, float scale) {
  int i = (blockIdx.x * 256 + threadIdx.x) * 8;
  if (i >= n) return;
  f32x4 a = *reinterpret_cast<const f32x4*>(in + i);
  f32x4 b = *reinterpret_cast<const f32x4*>(in + i + 4);
  union { u16 u[8]; uint4v v; } r;
#pragma unroll
  for (int j = 0; j < 4; ++j) {
    r.u[j]     = f2bf(a[j] * scale);
    r.u[4 + j] = f2bf(b[j] * scale);
  }
  *reinterpret_cast<uint4v*>(out + i) = r.v;
}

// fused 4-weight convert: out is one contiguous region [wq|wk|wv|wo]
__global__ __launch_bounds__(256) void conv_w4(const float* __restrict__ w0,
                                               const float* __restrict__ w1,
                                               const float* __restrict__ w2,
                                               const float* __restrict__ w3,
                                               u16* __restrict__ out, float s0) {
  int y = blockIdx.y;
  const float* src = (y == 0) ? w0 : (y == 1) ? w1 : (y == 2) ? w2 : w3;
  float scale = (y == 0) ? s0 : 1.0f;
  int i = (blockIdx.x * 256 + threadIdx.x) * 8;
  f32x4 a = *reinterpret_cast<const f32x4*>(src + i);
  f32x4 b = *reinterpret_cast<const f32x4*>(src + i + 4);
  union { u16 u[8]; uint4v v; } r;
#pragma unroll
  for (int j = 0; j < 4; ++j) {
    r.u[j]     = f2bf(a[j] * scale);
    r.u[4 + j] = f2bf(b[j] * scale);
  }
  *reinterpret_cast<uint4v*>(out + (size_t)y * (D_ * D_) + i) = r.v;
}

// ---------------- GEMM: C[M,N] = A[M,K] * B[N,K]^T ----------------
// MODE 0: QKV fused — cols [0,1024)->Qb, [1024,2048)->Kb, [2048,3072)->Vt^T.
// MODE 1: f32 out + bias (output projection).
template<int MODE>
__global__ __launch_bounds__(256) void gemm_bt(const u16* __restrict__ A,
                                               const u16* __restrict__ B,
                                               u16* __restrict__ Qb,
                                               u16* __restrict__ Kb,
                                               u16* __restrict__ Vt,
                                               float* __restrict__ Cf,
                                               const float* __restrict__ bias,
                                               int M, int N, int K) {
  __shared__ __attribute__((aligned(16))) u16 As[128 * 64];
  __shared__ __attribute__((aligned(16))) u16 Bs[128 * 64];

  const int t = threadIdx.x;
  const int l = t & 63;
  const int w = t >> 6;
  const int wr = w >> 1, wc = w & 1;
  const int m0 = blockIdx.y * 128;
  const int n0 = blockIdx.x * 128;

  f32x4 zero = {0.f, 0.f, 0.f, 0.f};
  f32x4 acc[4][4];
#pragma unroll
  for (int i = 0; i < 4; ++i)
#pragma unroll
    for (int j = 0; j < 4; ++j) acc[i][j] = zero;

  for (int k0 = 0; k0 < K; k0 += 64) {
    __syncthreads();
#pragma unroll
    for (int i = 0; i < 4; ++i) {
      int slot = i * 256 + t;
      int r = slot >> 3, c = slot & 7;
      const u16* srcA = A + (size_t)(m0 + r) * K + k0 + ((c ^ (r & 7)) * 8);
      gload_lds16(srcA, (char*)As + (size_t)(i * 256 + w * 64) * 16);
      const u16* srcB = B + (size_t)(n0 + r) * K + k0 + ((c ^ (r & 7)) * 8);
      gload_lds16(srcB, (char*)Bs + (size_t)(i * 256 + w * 64) * 16);
    }
    __syncthreads();

#pragma unroll
    for (int kc = 0; kc < 2; ++kc) {
      short8 a[4], bf[4];
      int lc = kc * 4 + (l >> 4);
#pragma unroll
      for (int i = 0; i < 4; ++i) {
        int ra = wr * 64 + i * 16 + (l & 15);
        a[i] = *reinterpret_cast<const short8*>(&As[ra * 64 + ((lc ^ (ra & 7)) * 8)]);
        int rb = wc * 64 + i * 16 + (l & 15);
        bf[i] = *reinterpret_cast<const short8*>(&Bs[rb * 64 + ((lc ^ (rb & 7)) * 8)]);
      }
#pragma unroll
      for (int mi = 0; mi < 4; ++mi)
#pragma unroll
        for (int ni = 0; ni < 4; ++ni)
          acc[mi][ni] = __builtin_amdgcn_mfma_f32_16x16x32_bf16(a[mi], bf[ni], acc[mi][ni], 0, 0, 0);
    }
  }

#pragma unroll
  for (int ni = 0; ni < 4; ++ni) {
    int col = n0 + wc * 64 + ni * 16 + (l & 15);
    float bv = (MODE == 1) ? bias[col] : 0.f;
#pragma unroll
    for (int mi = 0; mi < 4; ++mi) {
      int row0 = m0 + wr * 64 + mi * 16 + (l >> 4) * 4;
      if (MODE == 1) {
#pragma unroll
        for (int r = 0; r < 4; ++r)
          Cf[(size_t)(row0 + r) * N + col] = acc[mi][ni][r] + bv;
      } else {
        if (col < 2048) {
          u16* dst = (col < 1024) ? Qb : Kb;
          int c = col & 1023;
#pragma unroll
          for (int r = 0; r < 4; ++r)
            dst[(size_t)(row0 + r) * 1024 + c] = f2bf(acc[mi][ni][r]);
        } else {
          int vc = col - 2048;
          int bh = (row0 >> 11) * 16 + (vc >> 6);
          int s0 = row0 & 2047;
          u16x4 pk;
#pragma unroll
          for (int r = 0; r < 4; ++r) pk[r] = f2bf(acc[mi][ni][r]);
          *reinterpret_cast<u16x4*>(Vt + ((size_t)(bh * 64 + (vc & 63))) * 2048 + s0) = pk;
        }
      }
    }
  }
}

// ---------------- causal flash attention (swapped 32x32 structure) --------
// grid (S/128, B*H); block 256 = 4 waves; wave w owns q rows [qw, qw+32).
// Per lane: q = qw + (l&31); holds half the keys (hi = l>>5 selects which).
__global__ __launch_bounds__(256) void attn_fwd(const u16* __restrict__ Q,
                                                const u16* __restrict__ K,
                                                const u16* __restrict__ Vtg,
                                                u16* __restrict__ AO) {
  __shared__ __attribute__((aligned(16))) u16 smem[16384];  // 32 KiB
  u16* Ks0 = smem;            // [64][64] swizzled
  u16* Ks1 = smem + 4096;
  u16* Vs0 = smem + 8192;     // [d][64] swizzled
  u16* Vs1 = smem + 12288;

  const int t = threadIdx.x;
  const int l = t & 63;
  const int w = t >> 6;
  const int hi = l >> 5;
  const int hi8 = hi * 8, hi4 = hi * 4;
  const int q0 = blockIdx.x * 128;
  const int bh = blockIdx.y;
  const size_t qkbase = (size_t)((bh >> 4) * S_) * D_ + (bh & 15) * DK_;
  const u16* Vg = Vtg + (size_t)bh * 64 * S_;
  const int qw = q0 + w * 32;
  const int qi = qw + (l & 31);

  // Q fragments as B-operand: B[col=q=l&31][k=d chunk] (Q pre-scaled)
  short8 qf[4];
#pragma unroll
  for (int c = 0; c < 4; ++c)
    qf[c] = *reinterpret_cast<const short8*>(
        Q + qkbase + (size_t)qi * D_ + c * 16 + hi8);

  f32x16 oa0 = {0,0,0,0,0,0,0,0,0,0,0,0,0,0,0,0};
  f32x16 oa1 = {0,0,0,0,0,0,0,0,0,0,0,0,0,0,0,0};
  float m_r = -INFINITY, l_r = 0.f;

  const int nt = 2 * (blockIdx.x + 1);

  // stage tile 0
#pragma unroll
  for (int i = 0; i < 2; ++i) {
    int slot = i * 256 + t;
    int r = slot >> 3, c = t & 7;
    gload_lds16(K + qkbase + (size_t)r * D_ + ((c ^ (r & 7)) * 8),
                (char*)Ks0 + (size_t)(i * 256 + w * 64) * 16);
    gload_lds16(Vg + (size_t)r * S_ + ((c ^ (r & 7)) * 8),
                (char*)Vs0 + (size_t)(i * 256 + w * 64) * 16);
  }
  __syncthreads();

  for (int it = 0; it < nt; ++it) {
    const int cur = it & 1;
    const int j0 = it * 64;
    u16* ks = cur ? Ks1 : Ks0;
    u16* vs = cur ? Vs1 : Vs0;
    if (it + 1 < nt) {
      const int jn = j0 + 64;
      u16* ksn = cur ? Ks0 : Ks1;
      u16* vsn = cur ? Vs0 : Vs1;
#pragma unroll
      for (int i = 0; i < 2; ++i) {
        int slot = i * 256 + t;
        int r = slot >> 3, c = t & 7;
        gload_lds16(K + qkbase + (size_t)(jn + r) * D_ + ((c ^ (r & 7)) * 8),
                    (char*)ksn + (size_t)(i * 256 + w * 64) * 16);
        gload_lds16(Vg + (size_t)r * S_ + jn + ((c ^ (r & 7)) * 8),
                    (char*)vsn + (size_t)(i * 256 + w * 64) * 16);
      }
    }

    if (j0 <= qw + 31) {
      // S^T = K Q^T : C[col=q=l&31][row=key]
      f32x16 sa0 = {0,0,0,0,0,0,0,0,0,0,0,0,0,0,0,0};
      f32x16 sa1 = {0,0,0,0,0,0,0,0,0,0,0,0,0,0,0,0};
#pragma unroll
      for (int c = 0; c < 4; ++c) {
        int cl = 2 * c + hi;
        int k0r = l & 31, k1r = (l & 31) + 32;
        short8 kf0 = *reinterpret_cast<const short8*>(&ks[k0r * 64 + ((cl ^ (k0r & 7)) * 8)]);
        short8 kf1 = *reinterpret_cast<const short8*>(&ks[k1r * 64 + ((cl ^ (k1r & 7)) * 8)]);
        sa0 = __builtin_amdgcn_mfma_f32_32x32x16_bf16(kf0, qf[c], sa0, 0, 0, 0);
        sa1 = __builtin_amdgcn_mfma_f32_32x32x16_bf16(kf1, qf[c], sa1, 0, 0, 0);
      }
      // causal mask (diagonal tiles only)
      if (j0 + 63 > qw) {
#pragma unroll
        for (int r = 0; r < 16; ++r) {
          int key = j0 + (r & 3) + 8 * (r >> 2) + hi4;
          if (key > qi) sa0[r] = -INFINITY;
          if (key + 32 > qi) sa1[r] = -INFINITY;
        }
      }
      // online softmax: row is lane-local (32 vals) + partner exchange
      float mx = sa0[0];
#pragma unroll
      for (int r = 1; r < 16; ++r) mx = fmaxf(mx, sa0[r]);
#pragma unroll
      for (int r = 0; r < 16; ++r) mx = fmaxf(mx, sa1[r]);
      mx = fmaxf(mx, __shfl_xor(mx, 32));
      float mnew = fmaxf(m_r, mx);
      float rr = exp2f(m_r - mnew);
      m_r = mnew;
      float sum = 0.f;
#pragma unroll
      for (int r = 0; r < 16; ++r) { sa0[r] = exp2f(sa0[r] - mnew); sum += sa0[r]; }
#pragma unroll
      for (int r = 0; r < 16; ++r) { sa1[r] = exp2f(sa1[r] - mnew); sum += sa1[r]; }
      sum += __shfl_xor(sum, 32);
      l_r = l_r * rr + sum;
#pragma unroll
      for (int r = 0; r < 16; ++r) { oa0[r] *= rr; oa1[r] *= rr; }

      // P -> bf16 B-fragments via cvt_pk + permlane32_swap; O^T += V^T P^T
#pragma unroll
      for (int ksl = 0; ksl < 4; ++ksl) {
        const f32x16& ps = (ksl < 2) ? sa0 : sa1;
        const int b = 8 * (ksl & 1);
        u32 c0 = cvt_pk_bf16(ps[b + 0], ps[b + 1]);
        u32 c1 = cvt_pk_bf16(ps[b + 2], ps[b + 3]);
        u32 c2 = cvt_pk_bf16(ps[b + 4], ps[b + 5]);
        u32 c3 = cvt_pk_bf16(ps[b + 6], ps[b + 7]);
        pl32_swap(c0, c2);
        pl32_swap(c1, c3);
        union { u32 u[4]; short8 s; } pa;
        pa.u[0] = c0; pa.u[1] = c1; pa.u[2] = c2; pa.u[3] = c3;
        int cl = 2 * ksl + hi;
        int d0r = l & 31, d1r = (l & 31) + 32;
        short8 vf0 = *reinterpret_cast<const short8*>(&vs[d0r * 64 + ((cl ^ (d0r & 7)) * 8)]);
        short8 vf1 = *reinterpret_cast<const short8*>(&vs[d1r * 64 + ((cl ^ (d1r & 7)) * 8)]);
        oa0 = __builtin_amdgcn_mfma_f32_32x32x16_bf16(vf0, pa.s, oa0, 0, 0, 0);
        oa1 = __builtin_amdgcn_mfma_f32_32x32x16_bf16(vf1, pa.s, oa1, 0, 0, 0);
      }
    }
    __syncthreads();
  }

  // epilogue: normalize, bounce O^T -> row-major via LDS, 16B stores
  float inv = 1.0f / l_r;
  u16* Ob = smem + w * 2304;  // 32 rows x 72 u16 per wave
#pragma unroll
  for (int acc = 0; acc < 2; ++acc) {
    const f32x16& oo = acc ? oa1 : oa0;
#pragma unroll
    for (int rp = 0; rp < 8; ++rp) {
      u32 pk = cvt_pk_bf16(oo[2 * rp] * inv, oo[2 * rp + 1] * inv);
      int d0 = ((2 * rp) & 3) + 8 * (rp >> 1) + hi4 + 32 * acc;
      *reinterpret_cast<u32*>(&Ob[(l & 31) * 72 + d0]) = pk;
    }
  }
  __syncthreads();
  int qq = l >> 1;
  int chb = (l & 1) * 4;
#pragma unroll
  for (int c2 = 0; c2 < 4; ++c2) {
    uint4v vv = *reinterpret_cast<const uint4v*>(&Ob[qq * 72 + (chb + c2) * 8]);
    *reinterpret_cast<uint4v*>(&AO[qkbase + (size_t)(qw + qq) * D_ + (chb + c2) * 8]) = vv;
  }
}

// ---------------- launch ----------------
extern "C" void kernel_launch(void* const* d_in, const int* in_sizes, int n_in,
                              void* d_out, int out_size, void* d_ws, size_t ws_size,
                              hipStream_t stream) {
  const float* x  = (const float*)d_in[0];
  const float* wq = (const float*)d_in[1];
  const float* wk = (const float*)d_in[2];
  const float* wv = (const float*)d_in[3];
  const float* wo = (const float*)d_in[4];
  const float* bo = (const float*)d_in[5];
  float* out = (float*)d_out;

  char* ws = (char*)d_ws;
  u16* XB   = (u16*)(ws);                       // 16 MiB
  u16* WQKV = (u16*)(ws + (size_t)(16 << 20));  // 6 MiB (wq|wk|wv), then wo
  u16* WOB  = (u16*)(ws + (size_t)(22 << 20));  // 2 MiB (contiguous after WQKV)
  u16* Qb   = (u16*)(ws + (size_t)(24 << 20));
  u16* Kb   = (u16*)(ws + (size_t)(40 << 20));
  u16* Vt   = (u16*)(ws + (size_t)(56 << 20));  // [bh*64+d][s]
  u16* AO   = (u16*)(ws + (size_t)(72 << 20));

  const int nx = B_ * S_ * D_;   // 8388608
  const int nw = D_ * D_;        // 1048576

  conv_bf16<<<nx / 2048, 256, 0, stream>>>(x, XB, nx, 1.0f);
  // wq scale folds DK^-0.5 * log2(e) for exp2-domain softmax
  conv_w4<<<dim3(nw / 2048, 4), 256, 0, stream>>>(wq, wk, wv, wo, WQKV,
                                                  0.18033688011112042f);

  gemm_bt<0><<<dim3(3072 / 128, (B_ * S_) / 128), 256, 0, stream>>>(
      XB, WQKV, Qb, Kb, Vt, nullptr, nullptr, B_ * S_, 3072, D_);

  attn_fwd<<<dim3(S_ / 128, B_ * H_), 256, 0, stream>>>(Qb, Kb, Vt, AO);

  gemm_bt<1><<<dim3(D_ / 128, (B_ * S_) / 128), 256, 0, stream>>>(
      AO, WOB, nullptr, nullptr, nullptr, out, bo, B_ * S_, D_, D_);
}

// Round 4
// 244.558 us; speedup vs baseline: 1.7551x; 1.0346x over previous
//
#include <hip/hip_runtime.h>

typedef unsigned short u16;
typedef unsigned int u32;
typedef __attribute__((ext_vector_type(4))) u16 u16x4;
typedef __attribute__((ext_vector_type(8))) short short8;
typedef __attribute__((ext_vector_type(4))) float f32x4;
typedef __attribute__((ext_vector_type(16))) float f32x16;
typedef __attribute__((ext_vector_type(4))) u32 uint4v;

#define AS1 __attribute__((address_space(1)))
#define AS3 __attribute__((address_space(3)))

#define B_  4
#define S_  2048
#define D_  1024
#define H_  16
#define DK_ 64

__device__ __forceinline__ u16 f2bf(float f) {
  union { float f; unsigned u; } v; v.f = f;
  unsigned r = v.u + 0x7fffu + ((v.u >> 16) & 1u);
  return (u16)(r >> 16);
}

__device__ __forceinline__ u32 cvt_pk_bf16(float lo, float hi) {
  u32 r;
  asm("v_cvt_pk_bf16_f32 %0, %1, %2" : "=v"(r) : "v"(lo), "v"(hi));
  return r;
}

__device__ __forceinline__ void pl32_swap(u32& a, u32& b) {
  asm("v_permlane32_swap_b32 %0, %1" : "+v"(a), "+v"(b));
}

__device__ __forceinline__ void gload_lds16(const void* g, void* l) {
  __builtin_amdgcn_global_load_lds((const AS1 void*)g, (AS3 void*)l, 16, 0, 0);
}

// ---------------- fp32 -> bf16 convert ----------------
__global__ __launch_bounds__(256) void conv_bf16(const float* __restrict__ in,
                                                 u16* __restrict__ out,
                                                 int n, float scale) {
  int i = (blockIdx.x * 256 + threadIdx.x) * 8;
  if (i >= n) return;
  f32x4 a = *reinterpret_cast<const f32x4*>(in + i);
  f32x4 b = *reinterpret_cast<const f32x4*>(in + i + 4);
  union { u16 u[8]; uint4v v; } r;
#pragma unroll
  for (int j = 0; j < 4; ++j) {
    r.u[j]     = f2bf(a[j] * scale);
    r.u[4 + j] = f2bf(b[j] * scale);
  }
  *reinterpret_cast<uint4v*>(out + i) = r.v;
}

// fused 4-weight convert: out is one contiguous region [wq|wk|wv|wo]
__global__ __launch_bounds__(256) void conv_w4(const float* __restrict__ w0,
                                               const float* __restrict__ w1,
                                               const float* __restrict__ w2,
                                               const float* __restrict__ w3,
                                               u16* __restrict__ out, float s0) {
  int y = blockIdx.y;
  const float* src = (y == 0) ? w0 : (y == 1) ? w1 : (y == 2) ? w2 : w3;
  float scale = (y == 0) ? s0 : 1.0f;
  int i = (blockIdx.x * 256 + threadIdx.x) * 8;
  f32x4 a = *reinterpret_cast<const f32x4*>(src + i);
  f32x4 b = *reinterpret_cast<const f32x4*>(src + i + 4);
  union { u16 u[8]; uint4v v; } r;
#pragma unroll
  for (int j = 0; j < 4; ++j) {
    r.u[j]     = f2bf(a[j] * scale);
    r.u[4 + j] = f2bf(b[j] * scale);
  }
  *reinterpret_cast<uint4v*>(out + (size_t)y * (D_ * D_) + i) = r.v;
}

// ---------------- GEMM: C[M,N] = A[M,K] * B[N,K]^T ----------------
template<int MODE>
__global__ __launch_bounds__(256) void gemm_bt(const u16* __restrict__ A,
                                               const u16* __restrict__ B,
                                               u16* __restrict__ Qb,
                                               u16* __restrict__ Kb,
                                               u16* __restrict__ Vt,
                                               float* __restrict__ Cf,
                                               const float* __restrict__ bias,
                                               int M, int N, int K) {
  __shared__ __attribute__((aligned(16))) u16 As[128 * 64];
  __shared__ __attribute__((aligned(16))) u16 Bs[128 * 64];

  const int t = threadIdx.x;
  const int l = t & 63;
  const int w = t >> 6;
  const int wr = w >> 1, wc = w & 1;
  const int m0 = blockIdx.y * 128;
  const int n0 = blockIdx.x * 128;

  f32x4 zero = {0.f, 0.f, 0.f, 0.f};
  f32x4 acc[4][4];
#pragma unroll
  for (int i = 0; i < 4; ++i)
#pragma unroll
    for (int j = 0; j < 4; ++j) acc[i][j] = zero;

  for (int k0 = 0; k0 < K; k0 += 64) {
    __syncthreads();
#pragma unroll
    for (int i = 0; i < 4; ++i) {
      int slot = i * 256 + t;
      int r = slot >> 3, c = slot & 7;
      const u16* srcA = A + (size_t)(m0 + r) * K + k0 + ((c ^ (r & 7)) * 8);
      gload_lds16(srcA, (char*)As + (size_t)(i * 256 + w * 64) * 16);
      const u16* srcB = B + (size_t)(n0 + r) * K + k0 + ((c ^ (r & 7)) * 8);
      gload_lds16(srcB, (char*)Bs + (size_t)(i * 256 + w * 64) * 16);
    }
    __syncthreads();

#pragma unroll
    for (int kc = 0; kc < 2; ++kc) {
      short8 a[4], bf[4];
      int lc = kc * 4 + (l >> 4);
#pragma unroll
      for (int i = 0; i < 4; ++i) {
        int ra = wr * 64 + i * 16 + (l & 15);
        a[i] = *reinterpret_cast<const short8*>(&As[ra * 64 + ((lc ^ (ra & 7)) * 8)]);
        int rb = wc * 64 + i * 16 + (l & 15);
        bf[i] = *reinterpret_cast<const short8*>(&Bs[rb * 64 + ((lc ^ (rb & 7)) * 8)]);
      }
#pragma unroll
      for (int mi = 0; mi < 4; ++mi)
#pragma unroll
        for (int ni = 0; ni < 4; ++ni)
          acc[mi][ni] = __builtin_amdgcn_mfma_f32_16x16x32_bf16(a[mi], bf[ni], acc[mi][ni], 0, 0, 0);
    }
  }

#pragma unroll
  for (int ni = 0; ni < 4; ++ni) {
    int col = n0 + wc * 64 + ni * 16 + (l & 15);
    float bv = (MODE == 1) ? bias[col] : 0.f;
#pragma unroll
    for (int mi = 0; mi < 4; ++mi) {
      int row0 = m0 + wr * 64 + mi * 16 + (l >> 4) * 4;
      if (MODE == 1) {
#pragma unroll
        for (int r = 0; r < 4; ++r)
          Cf[(size_t)(row0 + r) * N + col] = acc[mi][ni][r] + bv;
      } else {
        if (col < 2048) {
          u16* dst = (col < 1024) ? Qb : Kb;
          int c = col & 1023;
#pragma unroll
          for (int r = 0; r < 4; ++r)
            dst[(size_t)(row0 + r) * 1024 + c] = f2bf(acc[mi][ni][r]);
        } else {
          int vc = col - 2048;
          int bh = (row0 >> 11) * 16 + (vc >> 6);
          int s0 = row0 & 2047;
          u16x4 pk;
#pragma unroll
          for (int r = 0; r < 4; ++r) pk[r] = f2bf(acc[mi][ni][r]);
          *reinterpret_cast<u16x4*>(Vt + ((size_t)(bh * 64 + (vc & 63))) * 2048 + s0) = pk;
        }
      }
    }
  }
}

// ---------------- causal flash attention (paired supertiles) --------------
// grid (8, B*H); block handles q-supertiles bx and 15-bx (128 rows each).
// Wave w owns rows [T*128 + w*32, +32) of each. Shared K/V staging+frags.
__global__ __launch_bounds__(256) void attn_fwd(const u16* __restrict__ Q,
                                                const u16* __restrict__ K,
                                                const u16* __restrict__ Vtg,
                                                u16* __restrict__ AO) {
  __shared__ __attribute__((aligned(16))) u16 smem[16384];  // 32 KiB
  u16* Ks0 = smem;
  u16* Ks1 = smem + 4096;
  u16* Vs0 = smem + 8192;
  u16* Vs1 = smem + 12288;

  const int t = threadIdx.x;
  const int l = t & 63;
  const int w = t >> 6;
  const int hi = l >> 5;
  const int hi8 = hi * 8, hi4 = hi * 4;
  const int bx = blockIdx.x;
  const int bh = blockIdx.y;
  const size_t qkbase = (size_t)((bh >> 4) * S_) * D_ + (bh & 15) * DK_;
  const u16* Vg = Vtg + (size_t)bh * 64 * S_;

  const int qwL = bx * 128 + w * 32;
  const int qwH = (15 - bx) * 128 + w * 32;
  const int qiL = qwL + (l & 31);
  const int qiH = qwH + (l & 31);

  short8 qfL[4], qfH[4];
#pragma unroll
  for (int c = 0; c < 4; ++c) {
    qfL[c] = *reinterpret_cast<const short8*>(Q + qkbase + (size_t)qiL * D_ + c * 16 + hi8);
    qfH[c] = *reinterpret_cast<const short8*>(Q + qkbase + (size_t)qiH * D_ + c * 16 + hi8);
  }

  f32x16 oL0 = {0,0,0,0,0,0,0,0,0,0,0,0,0,0,0,0};
  f32x16 oL1 = {0,0,0,0,0,0,0,0,0,0,0,0,0,0,0,0};
  f32x16 oH0 = {0,0,0,0,0,0,0,0,0,0,0,0,0,0,0,0};
  f32x16 oH1 = {0,0,0,0,0,0,0,0,0,0,0,0,0,0,0,0};
  float mL = -INFINITY, lL = 0.f, mH = -INFINITY, lH = 0.f;

  const int nst = 2 * (16 - bx);  // staged k-tiles = hi supertile's range

  // softmax + defer-max update (T13); s becomes P in-place
  auto smax = [&](f32x16& s0, f32x16& s1, float& m, float& ls,
                  f32x16& o0, f32x16& o1) {
    float mx = s0[0];
#pragma unroll
    for (int r = 1; r < 16; ++r) mx = fmaxf(mx, s0[r]);
#pragma unroll
    for (int r = 0; r < 16; ++r) mx = fmaxf(mx, s1[r]);
    mx = fmaxf(mx, __shfl_xor(mx, 32));
    if (!__all(mx <= m + 11.0f)) {
      float mnew = fmaxf(m, mx);
      float rr = exp2f(m - mnew);
      m = mnew;
      ls *= rr;
#pragma unroll
      for (int r = 0; r < 16; ++r) { o0[r] *= rr; o1[r] *= rr; }
    }
    float sum = 0.f;
#pragma unroll
    for (int r = 0; r < 16; ++r) { s0[r] = exp2f(s0[r] - m); sum += s0[r]; }
#pragma unroll
    for (int r = 0; r < 16; ++r) { s1[r] = exp2f(s1[r] - m); sum += s1[r]; }
    sum += __shfl_xor(sum, 32);
    ls += sum;
  };

  // stage tile 0
#pragma unroll
  for (int i = 0; i < 2; ++i) {
    int slot = i * 256 + t;
    int r = slot >> 3, c = t & 7;
    gload_lds16(K + qkbase + (size_t)r * D_ + ((c ^ (r & 7)) * 8),
                (char*)Ks0 + (size_t)(i * 256 + w * 64) * 16);
    gload_lds16(Vg + (size_t)r * S_ + ((c ^ (r & 7)) * 8),
                (char*)Vs0 + (size_t)(i * 256 + w * 64) * 16);
  }
  __syncthreads();

  for (int it = 0; it < nst; ++it) {
    const int cur = it & 1;
    const int j0 = it * 64;
    u16* ks = cur ? Ks1 : Ks0;
    u16* vs = cur ? Vs1 : Vs0;
    if (it + 1 < nst) {
      const int jn = j0 + 64;
      u16* ksn = cur ? Ks0 : Ks1;
      u16* vsn = cur ? Vs0 : Vs1;
#pragma unroll
      for (int i = 0; i < 2; ++i) {
        int slot = i * 256 + t;
        int r = slot >> 3, c = t & 7;
        gload_lds16(K + qkbase + (size_t)(jn + r) * D_ + ((c ^ (r & 7)) * 8),
                    (char*)ksn + (size_t)(i * 256 + w * 64) * 16);
        gload_lds16(Vg + (size_t)r * S_ + jn + ((c ^ (r & 7)) * 8),
                    (char*)vsn + (size_t)(i * 256 + w * 64) * 16);
      }
    }

    const bool actL = (j0 <= qwL + 31);
    const bool actH = (j0 <= qwH + 31);
    if (actH) {
      f32x16 sL0 = {0,0,0,0,0,0,0,0,0,0,0,0,0,0,0,0};
      f32x16 sL1 = {0,0,0,0,0,0,0,0,0,0,0,0,0,0,0,0};
      f32x16 sH0 = {0,0,0,0,0,0,0,0,0,0,0,0,0,0,0,0};
      f32x16 sH1 = {0,0,0,0,0,0,0,0,0,0,0,0,0,0,0,0};
#pragma unroll
      for (int c = 0; c < 4; ++c) {
        int cl = 2 * c + hi;
        int k0r = l & 31, k1r = (l & 31) + 32;
        short8 kf0 = *reinterpret_cast<const short8*>(&ks[k0r * 64 + ((cl ^ (k0r & 7)) * 8)]);
        short8 kf1 = *reinterpret_cast<const short8*>(&ks[k1r * 64 + ((cl ^ (k1r & 7)) * 8)]);
        sH0 = __builtin_amdgcn_mfma_f32_32x32x16_bf16(kf0, qfH[c], sH0, 0, 0, 0);
        sH1 = __builtin_amdgcn_mfma_f32_32x32x16_bf16(kf1, qfH[c], sH1, 0, 0, 0);
        if (actL) {
          sL0 = __builtin_amdgcn_mfma_f32_32x32x16_bf16(kf0, qfL[c], sL0, 0, 0, 0);
          sL1 = __builtin_amdgcn_mfma_f32_32x32x16_bf16(kf1, qfL[c], sL1, 0, 0, 0);
        }
      }
      if (j0 + 63 > qwH) {
#pragma unroll
        for (int r = 0; r < 16; ++r) {
          int key = j0 + (r & 3) + 8 * (r >> 2) + hi4;
          if (key > qiH) sH0[r] = -INFINITY;
          if (key + 32 > qiH) sH1[r] = -INFINITY;
        }
      }
      smax(sH0, sH1, mH, lH, oH0, oH1);
      if (actL) {
        if (j0 + 63 > qwL) {
#pragma unroll
          for (int r = 0; r < 16; ++r) {
            int key = j0 + (r & 3) + 8 * (r >> 2) + hi4;
            if (key > qiL) sL0[r] = -INFINITY;
            if (key + 32 > qiL) sL1[r] = -INFINITY;
          }
        }
        smax(sL0, sL1, mL, lL, oL0, oL1);
      }
      // PV: shared V fragments, both supertiles
#pragma unroll
      for (int ksl = 0; ksl < 4; ++ksl) {
        const int b = 8 * (ksl & 1);
        const f32x16& pH = (ksl < 2) ? sH0 : sH1;
        u32 h0 = cvt_pk_bf16(pH[b + 0], pH[b + 1]);
        u32 h1 = cvt_pk_bf16(pH[b + 2], pH[b + 3]);
        u32 h2 = cvt_pk_bf16(pH[b + 4], pH[b + 5]);
        u32 h3 = cvt_pk_bf16(pH[b + 6], pH[b + 7]);
        pl32_swap(h0, h2);
        pl32_swap(h1, h3);
        union { u32 u[4]; short8 s; } paH;
        paH.u[0] = h0; paH.u[1] = h1; paH.u[2] = h2; paH.u[3] = h3;
        int cl = 2 * ksl + hi;
        int d0r = l & 31, d1r = (l & 31) + 32;
        short8 vf0 = *reinterpret_cast<const short8*>(&vs[d0r * 64 + ((cl ^ (d0r & 7)) * 8)]);
        short8 vf1 = *reinterpret_cast<const short8*>(&vs[d1r * 64 + ((cl ^ (d1r & 7)) * 8)]);
        oH0 = __builtin_amdgcn_mfma_f32_32x32x16_bf16(vf0, paH.s, oH0, 0, 0, 0);
        oH1 = __builtin_amdgcn_mfma_f32_32x32x16_bf16(vf1, paH.s, oH1, 0, 0, 0);
        if (actL) {
          const f32x16& pL = (ksl < 2) ? sL0 : sL1;
          u32 g0 = cvt_pk_bf16(pL[b + 0], pL[b + 1]);
          u32 g1 = cvt_pk_bf16(pL[b + 2], pL[b + 3]);
          u32 g2 = cvt_pk_bf16(pL[b + 4], pL[b + 5]);
          u32 g3 = cvt_pk_bf16(pL[b + 6], pL[b + 7]);
          pl32_swap(g0, g2);
          pl32_swap(g1, g3);
          union { u32 u[4]; short8 s; } paL;
          paL.u[0] = g0; paL.u[1] = g1; paL.u[2] = g2; paL.u[3] = g3;
          oL0 = __builtin_amdgcn_mfma_f32_32x32x16_bf16(vf0, paL.s, oL0, 0, 0, 0);
          oL1 = __builtin_amdgcn_mfma_f32_32x32x16_bf16(vf1, paL.s, oL1, 0, 0, 0);
        }
      }
    }
    __syncthreads();
  }

  // epilogue: normalize, bounce O^T -> row-major via per-wave LDS, 16B stores
  u16* Ob = smem + w * 2304;  // 32 rows x 72 u16 per wave
#pragma unroll
  for (int st = 0; st < 2; ++st) {
    float inv = 1.0f / (st ? lH : lL);
    int qw = st ? qwH : qwL;
#pragma unroll
    for (int acc = 0; acc < 2; ++acc) {
      const f32x16& oo = st ? (acc ? oH1 : oH0) : (acc ? oL1 : oL0);
#pragma unroll
      for (int rp = 0; rp < 8; ++rp) {
        u32 pk = cvt_pk_bf16(oo[2 * rp] * inv, oo[2 * rp + 1] * inv);
        int d0 = ((2 * rp) & 3) + 8 * (rp >> 1) + hi4 + 32 * acc;
        *reinterpret_cast<u32*>(&Ob[(l & 31) * 72 + d0]) = pk;
      }
    }
    int qq = l >> 1;
    int chb = (l & 1) * 4;
#pragma unroll
    for (int c2 = 0; c2 < 4; ++c2) {
      uint4v vv = *reinterpret_cast<const uint4v*>(&Ob[qq * 72 + (chb + c2) * 8]);
      *reinterpret_cast<uint4v*>(&AO[qkbase + (size_t)(qw - w * 32 + w * 32 + qq) * D_ + (chb + c2) * 8]) = vv;
    }
  }
}

// ---------------- launch ----------------
extern "C" void kernel_launch(void* const* d_in, const int* in_sizes, int n_in,
                              void* d_out, int out_size, void* d_ws, size_t ws_size,
                              hipStream_t stream) {
  const float* x  = (const float*)d_in[0];
  const float* wq = (const float*)d_in[1];
  const float* wk = (const float*)d_in[2];
  const float* wv = (const float*)d_in[3];
  const float* wo = (const float*)d_in[4];
  const float* bo = (const float*)d_in[5];
  float* out = (float*)d_out;

  char* ws = (char*)d_ws;
  u16* XB   = (u16*)(ws);                       // 16 MiB
  u16* WQKV = (u16*)(ws + (size_t)(16 << 20));  // 6 MiB (wq|wk|wv), then wo
  u16* WOB  = (u16*)(ws + (size_t)(22 << 20));  // 2 MiB
  u16* Qb   = (u16*)(ws + (size_t)(24 << 20));
  u16* Kb   = (u16*)(ws + (size_t)(40 << 20));
  u16* Vt   = (u16*)(ws + (size_t)(56 << 20));  // [bh*64+d][s]
  u16* AO   = (u16*)(ws + (size_t)(72 << 20));

  const int nx = B_ * S_ * D_;   // 8388608
  const int nw = D_ * D_;        // 1048576

  conv_bf16<<<nx / 2048, 256, 0, stream>>>(x, XB, nx, 1.0f);
  // wq scale folds DK^-0.5 * log2(e) for exp2-domain softmax
  conv_w4<<<dim3(nw / 2048, 4), 256, 0, stream>>>(wq, wk, wv, wo, WQKV,
                                                  0.18033688011112042f);

  gemm_bt<0><<<dim3(3072 / 128, (B_ * S_) / 128), 256, 0, stream>>>(
      XB, WQKV, Qb, Kb, Vt, nullptr, nullptr, B_ * S_, 3072, D_);

  attn_fwd<<<dim3(8, B_ * H_), 256, 0, stream>>>(Qb, Kb, Vt, AO);

  gemm_bt<1><<<dim3(D_ / 128, (B_ * S_) / 128), 256, 0, stream>>>(
      AO, WOB, nullptr, nullptr, nullptr, out, bo, B_ * S_, D_, D_);
}

// Round 6
// 236.190 us; speedup vs baseline: 1.8173x; 1.0354x over previous
//
#include <hip/hip_runtime.h>

typedef unsigned short u16;
typedef unsigned int u32;
typedef __attribute__((ext_vector_type(4))) u16 u16x4;
typedef __attribute__((ext_vector_type(8))) short short8;
typedef __attribute__((ext_vector_type(4))) float f32x4;
typedef __attribute__((ext_vector_type(16))) float f32x16;
typedef __attribute__((ext_vector_type(4))) u32 uint4v;

#define AS1 __attribute__((address_space(1)))
#define AS3 __attribute__((address_space(3)))

#define B_  4
#define S_  2048
#define D_  1024
#define H_  16
#define DK_ 64

#define WAIT_VM(n) asm volatile("s_waitcnt vmcnt(" #n ")" ::: "memory")
#define WAIT_LGK0  asm volatile("s_waitcnt lgkmcnt(0)" ::: "memory")

__device__ __forceinline__ u16 f2bf(float f) {
  union { float f; unsigned u; } v; v.f = f;
  unsigned r = v.u + 0x7fffu + ((v.u >> 16) & 1u);
  return (u16)(r >> 16);
}

__device__ __forceinline__ u32 cvt_pk_bf16(float lo, float hi) {
  u32 r;
  asm("v_cvt_pk_bf16_f32 %0, %1, %2" : "=v"(r) : "v"(lo), "v"(hi));
  return r;
}

__device__ __forceinline__ void pl32_swap(u32& a, u32& b) {
  asm("v_permlane32_swap_b32 %0, %1" : "+v"(a), "+v"(b));
}

__device__ __forceinline__ void gload_lds16(const void* g, void* l) {
  __builtin_amdgcn_global_load_lds((const AS1 void*)g, (AS3 void*)l, 16, 0, 0);
}

// ---------------- fp32 -> bf16 convert ----------------
__global__ __launch_bounds__(256) void conv_bf16(const float* __restrict__ in,
                                                 u16* __restrict__ out,
                                                 int n, float scale) {
  int i = (blockIdx.x * 256 + threadIdx.x) * 8;
  if (i >= n) return;
  f32x4 a = *reinterpret_cast<const f32x4*>(in + i);
  f32x4 b = *reinterpret_cast<const f32x4*>(in + i + 4);
  union { u16 u[8]; uint4v v; } r;
#pragma unroll
  for (int j = 0; j < 4; ++j) {
    r.u[j]     = f2bf(a[j] * scale);
    r.u[4 + j] = f2bf(b[j] * scale);
  }
  *reinterpret_cast<uint4v*>(out + i) = r.v;
}

// fused 4-weight convert: out is one contiguous region [wq|wk|wv|wo]
__global__ __launch_bounds__(256) void conv_w4(const float* __restrict__ w0,
                                               const float* __restrict__ w1,
                                               const float* __restrict__ w2,
                                               const float* __restrict__ w3,
                                               u16* __restrict__ out, float s0) {
  int y = blockIdx.y;
  const float* src = (y == 0) ? w0 : (y == 1) ? w1 : (y == 2) ? w2 : w3;
  float scale = (y == 0) ? s0 : 1.0f;
  int i = (blockIdx.x * 256 + threadIdx.x) * 8;
  f32x4 a = *reinterpret_cast<const f32x4*>(src + i);
  f32x4 b = *reinterpret_cast<const f32x4*>(src + i + 4);
  union { u16 u[8]; uint4v v; } r;
#pragma unroll
  for (int j = 0; j < 4; ++j) {
    r.u[j]     = f2bf(a[j] * scale);
    r.u[4 + j] = f2bf(b[j] * scale);
  }
  *reinterpret_cast<uint4v*>(out + (size_t)y * (D_ * D_) + i) = r.v;
}

// ---------------- GEMM: C[M,N] = A[M,K] * B[N,K]^T ----------------
template<int MODE>
__global__ __launch_bounds__(256) void gemm_bt(const u16* __restrict__ A,
                                               const u16* __restrict__ B,
                                               u16* __restrict__ Qb,
                                               u16* __restrict__ Kb,
                                               u16* __restrict__ Vt,
                                               float* __restrict__ Cf,
                                               const float* __restrict__ bias,
                                               int M, int N, int K) {
  __shared__ __attribute__((aligned(16))) u16 As[128 * 64];
  __shared__ __attribute__((aligned(16))) u16 Bs[128 * 64];

  const int t = threadIdx.x;
  const int l = t & 63;
  const int w = t >> 6;
  const int wr = w >> 1, wc = w & 1;
  const int m0 = blockIdx.y * 128;
  const int n0 = blockIdx.x * 128;

  f32x4 zero = {0.f, 0.f, 0.f, 0.f};
  f32x4 acc[4][4];
#pragma unroll
  for (int i = 0; i < 4; ++i)
#pragma unroll
    for (int j = 0; j < 4; ++j) acc[i][j] = zero;

  for (int k0 = 0; k0 < K; k0 += 64) {
    __syncthreads();
#pragma unroll
    for (int i = 0; i < 4; ++i) {
      int slot = i * 256 + t;
      int r = slot >> 3, c = slot & 7;
      const u16* srcA = A + (size_t)(m0 + r) * K + k0 + ((c ^ (r & 7)) * 8);
      gload_lds16(srcA, (char*)As + (size_t)(i * 256 + w * 64) * 16);
      const u16* srcB = B + (size_t)(n0 + r) * K + k0 + ((c ^ (r & 7)) * 8);
      gload_lds16(srcB, (char*)Bs + (size_t)(i * 256 + w * 64) * 16);
    }
    __syncthreads();

#pragma unroll
    for (int kc = 0; kc < 2; ++kc) {
      short8 a[4], bf[4];
      int lc = kc * 4 + (l >> 4);
#pragma unroll
      for (int i = 0; i < 4; ++i) {
        int ra = wr * 64 + i * 16 + (l & 15);
        a[i] = *reinterpret_cast<const short8*>(&As[ra * 64 + ((lc ^ (ra & 7)) * 8)]);
        int rb = wc * 64 + i * 16 + (l & 15);
        bf[i] = *reinterpret_cast<const short8*>(&Bs[rb * 64 + ((lc ^ (rb & 7)) * 8)]);
      }
#pragma unroll
      for (int mi = 0; mi < 4; ++mi)
#pragma unroll
        for (int ni = 0; ni < 4; ++ni)
          acc[mi][ni] = __builtin_amdgcn_mfma_f32_16x16x32_bf16(a[mi], bf[ni], acc[mi][ni], 0, 0, 0);
    }
  }

#pragma unroll
  for (int ni = 0; ni < 4; ++ni) {
    int col = n0 + wc * 64 + ni * 16 + (l & 15);
    float bv = (MODE == 1) ? bias[col] : 0.f;
#pragma unroll
    for (int mi = 0; mi < 4; ++mi) {
      int row0 = m0 + wr * 64 + mi * 16 + (l >> 4) * 4;
      if (MODE == 1) {
#pragma unroll
        for (int r = 0; r < 4; ++r)
          Cf[(size_t)(row0 + r) * N + col] = acc[mi][ni][r] + bv;
      } else {
        if (col < 2048) {
          u16* dst = (col < 1024) ? Qb : Kb;
          int c = col & 1023;
#pragma unroll
          for (int r = 0; r < 4; ++r)
            dst[(size_t)(row0 + r) * 1024 + c] = f2bf(acc[mi][ni][r]);
        } else {
          int vc = col - 2048;
          int bh = (row0 >> 11) * 16 + (vc >> 6);
          int s0 = row0 & 2047;
          u16x4 pk;
#pragma unroll
          for (int r = 0; r < 4; ++r) pk[r] = f2bf(acc[mi][ni][r]);
          *reinterpret_cast<u16x4*>(Vt + ((size_t)(bh * 64 + (vc & 63))) * 2048 + s0) = pk;
        }
      }
    }
  }
}

// ---------------- causal flash attention -----------------------------------
// grid (B*H, 8): blockIdx.x = bh, blockIdx.y = pair idx (supertiles bx, 15-bx).
// Triple-buffered K/V staging with counted vmcnt; R4-proven compute internals.
__global__ __launch_bounds__(256) void attn_fwd(const u16* __restrict__ Q,
                                                const u16* __restrict__ K,
                                                const u16* __restrict__ Vtg,
                                                u16* __restrict__ AO) {
  __shared__ __attribute__((aligned(16))) u16 smem[24576];  // 48 KiB
  u16* Ksb = smem;           // 3 bufs x [64][64] swizzled
  u16* Vsb = smem + 12288;   // 3 bufs x [d][64] swizzled

  const int t = threadIdx.x;
  const int l = t & 63;
  const int w = t >> 6;
  const int hi = l >> 5;
  const int hi8 = hi * 8, hi4 = hi * 4;
  const int bh = blockIdx.x;
  const int bx = blockIdx.y;
  const size_t qkbase = (size_t)((bh >> 4) * S_) * D_ + (bh & 15) * DK_;
  const u16* Vg = Vtg + (size_t)bh * 64 * S_;

  const int qwL = bx * 128 + w * 32;
  const int qwH = (15 - bx) * 128 + w * 32;
  const int qiL = qwL + (l & 31);
  const int qiH = qwH + (l & 31);

  short8 qfL[4], qfH[4];
#pragma unroll
  for (int c = 0; c < 4; ++c) {
    qfL[c] = *reinterpret_cast<const short8*>(Q + qkbase + (size_t)qiL * D_ + c * 16 + hi8);
    qfH[c] = *reinterpret_cast<const short8*>(Q + qkbase + (size_t)qiH * D_ + c * 16 + hi8);
  }

  f32x16 oL0 = {0,0,0,0,0,0,0,0,0,0,0,0,0,0,0,0};
  f32x16 oL1 = {0,0,0,0,0,0,0,0,0,0,0,0,0,0,0,0};
  f32x16 oH0 = {0,0,0,0,0,0,0,0,0,0,0,0,0,0,0,0};
  f32x16 oH1 = {0,0,0,0,0,0,0,0,0,0,0,0,0,0,0,0};
  float mL = -INFINITY, lL = 0.f, mH = -INFINITY, lH = 0.f;

  const int nst = 2 * (16 - bx);  // 18..32, always > 3

  // stage k-tile jt into LDS buffers (4 gload_lds per wave)
  auto stage = [&](int jt, u16* kdst, u16* vdst) {
    const u16* Ksrc = K + qkbase + (size_t)(jt * 64) * D_;
    const u16* Vsrc = Vg + jt * 64;
#pragma unroll
    for (int i = 0; i < 2; ++i) {
      int slot = i * 256 + t;
      int r = slot >> 3, c = t & 7;
      gload_lds16(Ksrc + (size_t)r * D_ + ((c ^ (r & 7)) * 8),
                  (char*)kdst + (size_t)(i * 256 + w * 64) * 16);
      gload_lds16(Vsrc + (size_t)r * S_ + ((c ^ (r & 7)) * 8),
                  (char*)vdst + (size_t)(i * 256 + w * 64) * 16);
    }
  };

  // R4-verbatim softmax with defer-max; s becomes P in-place
  auto smax = [&](f32x16& s0, f32x16& s1, float& m, float& ls,
                  f32x16& o0, f32x16& o1) {
    float mx = s0[0];
#pragma unroll
    for (int r = 1; r < 16; ++r) mx = fmaxf(mx, s0[r]);
#pragma unroll
    for (int r = 0; r < 16; ++r) mx = fmaxf(mx, s1[r]);
    mx = fmaxf(mx, __shfl_xor(mx, 32));
    if (!__all(mx <= m + 11.0f)) {
      float mnew = fmaxf(m, mx);
      float rr = exp2f(m - mnew);
      m = mnew;
      ls *= rr;
#pragma unroll
      for (int r = 0; r < 16; ++r) { o0[r] *= rr; o1[r] *= rr; }
    }
    float sum = 0.f;
#pragma unroll
    for (int r = 0; r < 16; ++r) { s0[r] = exp2f(s0[r] - m); sum += s0[r]; }
#pragma unroll
    for (int r = 0; r < 16; ++r) { s1[r] = exp2f(s1[r] - m); sum += s1[r]; }
    sum += __shfl_xor(sum, 32);
    ls += sum;
  };

  // prologue: 3 tiles in flight
  stage(0, Ksb, Vsb);
  stage(1, Ksb + 4096, Vsb + 4096);
  stage(2, Ksb + 8192, Vsb + 8192);
  int o0b = 0, o1b = 4096, o2b = 8192;

  for (int it = 0; it < nst; ++it) {
    // wait only for the oldest tile's loads (4/wave); keep 8 in flight
    if (it < nst - 2)       { WAIT_VM(8); }
    else if (it == nst - 2) { WAIT_VM(4); }
    else                    { WAIT_VM(0); }
    __builtin_amdgcn_s_barrier();
    __builtin_amdgcn_sched_barrier(0);

    const int j0 = it * 64;
    u16* ks = Ksb + o0b;
    u16* vs = Vsb + o0b;

    const bool actL = (j0 <= qwL + 31);
    const bool actH = (j0 <= qwH + 31);
    if (actH) {
      f32x16 sL0 = {0,0,0,0,0,0,0,0,0,0,0,0,0,0,0,0};
      f32x16 sL1 = {0,0,0,0,0,0,0,0,0,0,0,0,0,0,0,0};
      f32x16 sH0 = {0,0,0,0,0,0,0,0,0,0,0,0,0,0,0,0};
      f32x16 sH1 = {0,0,0,0,0,0,0,0,0,0,0,0,0,0,0,0};
#pragma unroll
      for (int c = 0; c < 4; ++c) {
        int cl = 2 * c + hi;
        int k0r = l & 31, k1r = (l & 31) + 32;
        short8 kf0 = *reinterpret_cast<const short8*>(&ks[k0r * 64 + ((cl ^ (k0r & 7)) * 8)]);
        short8 kf1 = *reinterpret_cast<const short8*>(&ks[k1r * 64 + ((cl ^ (k1r & 7)) * 8)]);
        sH0 = __builtin_amdgcn_mfma_f32_32x32x16_bf16(kf0, qfH[c], sH0, 0, 0, 0);
        sH1 = __builtin_amdgcn_mfma_f32_32x32x16_bf16(kf1, qfH[c], sH1, 0, 0, 0);
        if (actL) {
          sL0 = __builtin_amdgcn_mfma_f32_32x32x16_bf16(kf0, qfL[c], sL0, 0, 0, 0);
          sL1 = __builtin_amdgcn_mfma_f32_32x32x16_bf16(kf1, qfL[c], sL1, 0, 0, 0);
        }
      }
      if (j0 + 63 > qwH) {
#pragma unroll
        for (int r = 0; r < 16; ++r) {
          int key = j0 + (r & 3) + 8 * (r >> 2) + hi4;
          if (key > qiH) sH0[r] = -INFINITY;
          if (key + 32 > qiH) sH1[r] = -INFINITY;
        }
      }
      smax(sH0, sH1, mH, lH, oH0, oH1);
      if (actL) {
        if (j0 + 63 > qwL) {
#pragma unroll
          for (int r = 0; r < 16; ++r) {
            int key = j0 + (r & 3) + 8 * (r >> 2) + hi4;
            if (key > qiL) sL0[r] = -INFINITY;
            if (key + 32 > qiL) sL1[r] = -INFINITY;
          }
        }
        smax(sL0, sL1, mL, lL, oL0, oL1);
      }
      // PV: shared V fragments, both supertiles
#pragma unroll
      for (int ksl = 0; ksl < 4; ++ksl) {
        const int b = 8 * (ksl & 1);
        const f32x16& pH = (ksl < 2) ? sH0 : sH1;
        u32 h0 = cvt_pk_bf16(pH[b + 0], pH[b + 1]);
        u32 h1 = cvt_pk_bf16(pH[b + 2], pH[b + 3]);
        u32 h2 = cvt_pk_bf16(pH[b + 4], pH[b + 5]);
        u32 h3 = cvt_pk_bf16(pH[b + 6], pH[b + 7]);
        pl32_swap(h0, h2);
        pl32_swap(h1, h3);
        union { u32 u[4]; short8 s; } paH;
        paH.u[0] = h0; paH.u[1] = h1; paH.u[2] = h2; paH.u[3] = h3;
        int cl = 2 * ksl + hi;
        int d0r = l & 31, d1r = (l & 31) + 32;
        short8 vf0 = *reinterpret_cast<const short8*>(&vs[d0r * 64 + ((cl ^ (d0r & 7)) * 8)]);
        short8 vf1 = *reinterpret_cast<const short8*>(&vs[d1r * 64 + ((cl ^ (d1r & 7)) * 8)]);
        oH0 = __builtin_amdgcn_mfma_f32_32x32x16_bf16(vf0, paH.s, oH0, 0, 0, 0);
        oH1 = __builtin_amdgcn_mfma_f32_32x32x16_bf16(vf1, paH.s, oH1, 0, 0, 0);
        if (actL) {
          const f32x16& pL = (ksl < 2) ? sL0 : sL1;
          u32 g0 = cvt_pk_bf16(pL[b + 0], pL[b + 1]);
          u32 g1 = cvt_pk_bf16(pL[b + 2], pL[b + 3]);
          u32 g2 = cvt_pk_bf16(pL[b + 4], pL[b + 5]);
          u32 g3 = cvt_pk_bf16(pL[b + 6], pL[b + 7]);
          pl32_swap(g0, g2);
          pl32_swap(g1, g3);
          union { u32 u[4]; short8 s; } paL;
          paL.u[0] = g0; paL.u[1] = g1; paL.u[2] = g2; paL.u[3] = g3;
          oL0 = __builtin_amdgcn_mfma_f32_32x32x16_bf16(vf0, paL.s, oL0, 0, 0, 0);
          oL1 = __builtin_amdgcn_mfma_f32_32x32x16_bf16(vf1, paL.s, oL1, 0, 0, 0);
        }
      }
    }

    // reads of this buffer done -> safe to re-stage into it after barrier
    WAIT_LGK0;
    __builtin_amdgcn_sched_barrier(0);
    __builtin_amdgcn_s_barrier();
    if (it + 3 < nst) stage(it + 3, Ksb + o0b, Vsb + o0b);
    int tmp = o0b; o0b = o1b; o1b = o2b; o2b = tmp;
  }

  // epilogue: normalize, bounce O^T -> row-major via per-wave LDS, 16B stores
  u16* Ob = smem + w * 2304;  // 32 rows x 72 u16 per wave
#pragma unroll
  for (int st = 0; st < 2; ++st) {
    float inv = 1.0f / (st ? lH : lL);
    int qw = st ? qwH : qwL;
#pragma unroll
    for (int acc = 0; acc < 2; ++acc) {
      const f32x16& oo = st ? (acc ? oH1 : oH0) : (acc ? oL1 : oL0);
#pragma unroll
      for (int rp = 0; rp < 8; ++rp) {
        u32 pk = cvt_pk_bf16(oo[2 * rp] * inv, oo[2 * rp + 1] * inv);
        int d0 = ((2 * rp) & 3) + 8 * (rp >> 1) + hi4 + 32 * acc;
        *reinterpret_cast<u32*>(&Ob[(l & 31) * 72 + d0]) = pk;
      }
    }
    int qq = l >> 1;
    int chb = (l & 1) * 4;
#pragma unroll
    for (int c2 = 0; c2 < 4; ++c2) {
      uint4v vv = *reinterpret_cast<const uint4v*>(&Ob[qq * 72 + (chb + c2) * 8]);
      *reinterpret_cast<uint4v*>(&AO[qkbase + (size_t)(qw + qq) * D_ + (chb + c2) * 8]) = vv;
    }
  }
}

// ---------------- launch ----------------
extern "C" void kernel_launch(void* const* d_in, const int* in_sizes, int n_in,
                              void* d_out, int out_size, void* d_ws, size_t ws_size,
                              hipStream_t stream) {
  const float* x  = (const float*)d_in[0];
  const float* wq = (const float*)d_in[1];
  const float* wk = (const float*)d_in[2];
  const float* wv = (const float*)d_in[3];
  const float* wo = (const float*)d_in[4];
  const float* bo = (const float*)d_in[5];
  float* out = (float*)d_out;

  char* ws = (char*)d_ws;
  u16* XB   = (u16*)(ws);                       // 16 MiB
  u16* WQKV = (u16*)(ws + (size_t)(16 << 20));  // 6 MiB (wq|wk|wv), then wo
  u16* WOB  = (u16*)(ws + (size_t)(22 << 20));  // 2 MiB
  u16* Qb   = (u16*)(ws + (size_t)(24 << 20));
  u16* Kb   = (u16*)(ws + (size_t)(40 << 20));
  u16* Vt   = (u16*)(ws + (size_t)(56 << 20));  // [bh*64+d][s]
  u16* AO   = (u16*)(ws + (size_t)(72 << 20));

  const int nx = B_ * S_ * D_;   // 8388608
  const int nw = D_ * D_;        // 1048576

  conv_bf16<<<nx / 2048, 256, 0, stream>>>(x, XB, nx, 1.0f);
  // wq scale folds DK^-0.5 * log2(e) for exp2-domain softmax
  conv_w4<<<dim3(nw / 2048, 4), 256, 0, stream>>>(wq, wk, wv, wo, WQKV,
                                                  0.18033688011112042f);

  gemm_bt<0><<<dim3(3072 / 128, (B_ * S_) / 128), 256, 0, stream>>>(
      XB, WQKV, Qb, Kb, Vt, nullptr, nullptr, B_ * S_, 3072, D_);

  attn_fwd<<<dim3(B_ * H_, 8), 256, 0, stream>>>(Qb, Kb, Vt, AO);

  gemm_bt<1><<<dim3(D_ / 128, (B_ * S_) / 128), 256, 0, stream>>>(
      AO, WOB, nullptr, nullptr, nullptr, out, bo, B_ * S_, D_, D_);
}

// Round 7
// 182.998 us; speedup vs baseline: 2.3455x; 1.2907x over previous
//
#include <hip/hip_runtime.h>

typedef unsigned short u16;
typedef unsigned int u32;
typedef __attribute__((ext_vector_type(4))) u16 u16x4;
typedef __attribute__((ext_vector_type(8))) short short8;
typedef __attribute__((ext_vector_type(4))) float f32x4;
typedef __attribute__((ext_vector_type(16))) float f32x16;
typedef __attribute__((ext_vector_type(4))) u32 uint4v;

#define AS1 __attribute__((address_space(1)))
#define AS3 __attribute__((address_space(3)))

#define B_  4
#define S_  2048
#define D_  1024
#define H_  16
#define DK_ 64

#define WAIT_VM(n) asm volatile("s_waitcnt vmcnt(" #n ")" ::: "memory")
#define WAIT_LGK0  asm volatile("s_waitcnt lgkmcnt(0)" ::: "memory")

__device__ __forceinline__ u16 f2bf(float f) {
  union { float f; unsigned u; } v; v.f = f;
  unsigned r = v.u + 0x7fffu + ((v.u >> 16) & 1u);
  return (u16)(r >> 16);
}

__device__ __forceinline__ u32 cvt_pk_bf16(float lo, float hi) {
  u32 r;
  asm("v_cvt_pk_bf16_f32 %0, %1, %2" : "=v"(r) : "v"(lo), "v"(hi));
  return r;
}

__device__ __forceinline__ void pl32_swap(u32& a, u32& b) {
  asm("v_permlane32_swap_b32 %0, %1" : "+v"(a), "+v"(b));
}

__device__ __forceinline__ void gload_lds16(const void* g, void* l) {
  __builtin_amdgcn_global_load_lds((const AS1 void*)g, (AS3 void*)l, 16, 0, 0);
}

// ---------------- fp32 -> bf16 convert ----------------
__global__ __launch_bounds__(256) void conv_bf16(const float* __restrict__ in,
                                                 u16* __restrict__ out,
                                                 int n, float scale) {
  int i = (blockIdx.x * 256 + threadIdx.x) * 8;
  if (i >= n) return;
  f32x4 a = *reinterpret_cast<const f32x4*>(in + i);
  f32x4 b = *reinterpret_cast<const f32x4*>(in + i + 4);
  union { u16 u[8]; uint4v v; } r;
#pragma unroll
  for (int j = 0; j < 4; ++j) {
    r.u[j]     = f2bf(a[j] * scale);
    r.u[4 + j] = f2bf(b[j] * scale);
  }
  *reinterpret_cast<uint4v*>(out + i) = r.v;
}

// fused 4-weight convert: out is one contiguous region [wq|wk|wv|wo]
__global__ __launch_bounds__(256) void conv_w4(const float* __restrict__ w0,
                                               const float* __restrict__ w1,
                                               const float* __restrict__ w2,
                                               const float* __restrict__ w3,
                                               u16* __restrict__ out, float s0) {
  int y = blockIdx.y;
  const float* src = (y == 0) ? w0 : (y == 1) ? w1 : (y == 2) ? w2 : w3;
  float scale = (y == 0) ? s0 : 1.0f;
  int i = (blockIdx.x * 256 + threadIdx.x) * 8;
  f32x4 a = *reinterpret_cast<const f32x4*>(src + i);
  f32x4 b = *reinterpret_cast<const f32x4*>(src + i + 4);
  union { u16 u[8]; uint4v v; } r;
#pragma unroll
  for (int j = 0; j < 4; ++j) {
    r.u[j]     = f2bf(a[j] * scale);
    r.u[4 + j] = f2bf(b[j] * scale);
  }
  *reinterpret_cast<uint4v*>(out + (size_t)y * (D_ * D_) + i) = r.v;
}

// ---------------- GEMM: C[M,N] = A[M,K] * B[N,K]^T ----------------
template<int MODE>
__global__ __launch_bounds__(256) void gemm_bt(const u16* __restrict__ A,
                                               const u16* __restrict__ B,
                                               u16* __restrict__ Qb,
                                               u16* __restrict__ Kb,
                                               u16* __restrict__ Vt,
                                               float* __restrict__ Cf,
                                               const float* __restrict__ bias,
                                               int M, int N, int K) {
  __shared__ __attribute__((aligned(16))) u16 As[128 * 64];
  __shared__ __attribute__((aligned(16))) u16 Bs[128 * 64];

  const int t = threadIdx.x;
  const int l = t & 63;
  const int w = t >> 6;
  const int wr = w >> 1, wc = w & 1;
  const int m0 = blockIdx.y * 128;
  const int n0 = blockIdx.x * 128;

  f32x4 zero = {0.f, 0.f, 0.f, 0.f};
  f32x4 acc[4][4];
#pragma unroll
  for (int i = 0; i < 4; ++i)
#pragma unroll
    for (int j = 0; j < 4; ++j) acc[i][j] = zero;

  for (int k0 = 0; k0 < K; k0 += 64) {
    __syncthreads();
#pragma unroll
    for (int i = 0; i < 4; ++i) {
      int slot = i * 256 + t;
      int r = slot >> 3, c = slot & 7;
      const u16* srcA = A + (size_t)(m0 + r) * K + k0 + ((c ^ (r & 7)) * 8);
      gload_lds16(srcA, (char*)As + (size_t)(i * 256 + w * 64) * 16);
      const u16* srcB = B + (size_t)(n0 + r) * K + k0 + ((c ^ (r & 7)) * 8);
      gload_lds16(srcB, (char*)Bs + (size_t)(i * 256 + w * 64) * 16);
    }
    __syncthreads();

#pragma unroll
    for (int kc = 0; kc < 2; ++kc) {
      short8 a[4], bf[4];
      int lc = kc * 4 + (l >> 4);
#pragma unroll
      for (int i = 0; i < 4; ++i) {
        int ra = wr * 64 + i * 16 + (l & 15);
        a[i] = *reinterpret_cast<const short8*>(&As[ra * 64 + ((lc ^ (ra & 7)) * 8)]);
        int rb = wc * 64 + i * 16 + (l & 15);
        bf[i] = *reinterpret_cast<const short8*>(&Bs[rb * 64 + ((lc ^ (rb & 7)) * 8)]);
      }
#pragma unroll
      for (int mi = 0; mi < 4; ++mi)
#pragma unroll
        for (int ni = 0; ni < 4; ++ni)
          acc[mi][ni] = __builtin_amdgcn_mfma_f32_16x16x32_bf16(a[mi], bf[ni], acc[mi][ni], 0, 0, 0);
    }
  }

#pragma unroll
  for (int ni = 0; ni < 4; ++ni) {
    int col = n0 + wc * 64 + ni * 16 + (l & 15);
    float bv = (MODE == 1) ? bias[col] : 0.f;
#pragma unroll
    for (int mi = 0; mi < 4; ++mi) {
      int row0 = m0 + wr * 64 + mi * 16 + (l >> 4) * 4;
      if (MODE == 1) {
#pragma unroll
        for (int r = 0; r < 4; ++r)
          Cf[(size_t)(row0 + r) * N + col] = acc[mi][ni][r] + bv;
      } else {
        if (col < 2048) {
          u16* dst = (col < 1024) ? Qb : Kb;
          int c = col & 1023;
#pragma unroll
          for (int r = 0; r < 4; ++r)
            dst[(size_t)(row0 + r) * 1024 + c] = f2bf(acc[mi][ni][r]);
        } else {
          int vc = col - 2048;
          int bh = (row0 >> 11) * 16 + (vc >> 6);
          int s0 = row0 & 2047;
          u16x4 pk;
#pragma unroll
          for (int r = 0; r < 4; ++r) pk[r] = f2bf(acc[mi][ni][r]);
          *reinterpret_cast<u16x4*>(Vt + ((size_t)(bh * 64 + (vc & 63))) * 2048 + s0) = pk;
        }
      }
    }
  }
}

// ---------------- causal flash attention -----------------------------------
// grid (B*H, 16): blockIdx.x = bh; supertile s = 15 - blockIdx.y (LPT order:
// longest blocks dispatch first). One 128-row q-supertile per block, 4 waves
// x 32 rows. Triple-buffered K/V staging with counted vmcnt.
__global__ __launch_bounds__(256) void attn_fwd(const u16* __restrict__ Q,
                                                const u16* __restrict__ K,
                                                const u16* __restrict__ Vtg,
                                                u16* __restrict__ AO) {
  __shared__ __attribute__((aligned(16))) u16 smem[24576];  // 48 KiB
  u16* Ksb = smem;           // 3 bufs x [64][64] swizzled
  u16* Vsb = smem + 12288;   // 3 bufs x [d][64] swizzled

  const int t = threadIdx.x;
  const int l = t & 63;
  const int w = t >> 6;
  const int hi = l >> 5;
  const int hi8 = hi * 8, hi4 = hi * 4;
  const int bh = blockIdx.x;
  const int s = 15 - blockIdx.y;
  const size_t qkbase = (size_t)((bh >> 4) * S_) * D_ + (bh & 15) * DK_;
  const u16* Vg = Vtg + (size_t)bh * 64 * S_;

  const int qw = s * 128 + w * 32;
  const int qi = qw + (l & 31);

  short8 qf[4];
#pragma unroll
  for (int c = 0; c < 4; ++c)
    qf[c] = *reinterpret_cast<const short8*>(Q + qkbase + (size_t)qi * D_ + c * 16 + hi8);

  f32x16 o0 = {0,0,0,0,0,0,0,0,0,0,0,0,0,0,0,0};
  f32x16 o1 = {0,0,0,0,0,0,0,0,0,0,0,0,0,0,0,0};
  float m_r = -INFINITY, l_r = 0.f;

  const int nst = 2 * (s + 1);  // 2..32

  // stage k-tile jt into LDS buffers (4 gload_lds per wave)
  auto stage = [&](int jt, u16* kdst, u16* vdst) {
    const u16* Ksrc = K + qkbase + (size_t)(jt * 64) * D_;
    const u16* Vsrc = Vg + jt * 64;
#pragma unroll
    for (int i = 0; i < 2; ++i) {
      int slot = i * 256 + t;
      int r = slot >> 3, c = t & 7;
      gload_lds16(Ksrc + (size_t)r * D_ + ((c ^ (r & 7)) * 8),
                  (char*)kdst + (size_t)(i * 256 + w * 64) * 16);
      gload_lds16(Vsrc + (size_t)r * S_ + ((c ^ (r & 7)) * 8),
                  (char*)vdst + (size_t)(i * 256 + w * 64) * 16);
    }
  };

  // prologue: 3 tiles in flight (always valid: tiles 0..2 exist since S=2048)
  stage(0, Ksb, Vsb);
  stage(1, Ksb + 4096, Vsb + 4096);
  stage(2, Ksb + 8192, Vsb + 8192);
  int o0b = 0, o1b = 4096, o2b = 8192;

  for (int it = 0; it < nst; ++it) {
    if (it < nst - 2)       { WAIT_VM(8); }
    else if (it == nst - 2) { WAIT_VM(4); }
    else                    { WAIT_VM(0); }
    __builtin_amdgcn_s_barrier();
    __builtin_amdgcn_sched_barrier(0);

    const int j0 = it * 64;
    u16* ks = Ksb + o0b;
    u16* vs = Vsb + o0b;

    if (j0 <= qw + 31) {
      f32x16 s0 = {0,0,0,0,0,0,0,0,0,0,0,0,0,0,0,0};
      f32x16 s1 = {0,0,0,0,0,0,0,0,0,0,0,0,0,0,0,0};
#pragma unroll
      for (int c = 0; c < 4; ++c) {
        int cl = 2 * c + hi;
        int k0r = l & 31, k1r = (l & 31) + 32;
        short8 kf0 = *reinterpret_cast<const short8*>(&ks[k0r * 64 + ((cl ^ (k0r & 7)) * 8)]);
        short8 kf1 = *reinterpret_cast<const short8*>(&ks[k1r * 64 + ((cl ^ (k1r & 7)) * 8)]);
        s0 = __builtin_amdgcn_mfma_f32_32x32x16_bf16(kf0, qf[c], s0, 0, 0, 0);
        s1 = __builtin_amdgcn_mfma_f32_32x32x16_bf16(kf1, qf[c], s1, 0, 0, 0);
      }
      if (j0 + 63 > qw) {
#pragma unroll
        for (int r = 0; r < 16; ++r) {
          int key = j0 + (r & 3) + 8 * (r >> 2) + hi4;
          if (key > qi) s0[r] = -INFINITY;
          if (key + 32 > qi) s1[r] = -INFINITY;
        }
      }
      // online softmax with defer-max; s becomes P in-place
      {
        float mx = s0[0];
#pragma unroll
        for (int r = 1; r < 16; ++r) mx = fmaxf(mx, s0[r]);
#pragma unroll
        for (int r = 0; r < 16; ++r) mx = fmaxf(mx, s1[r]);
        mx = fmaxf(mx, __shfl_xor(mx, 32));
        if (!__all(mx <= m_r + 11.0f)) {
          float mnew = fmaxf(m_r, mx);
          float rr = exp2f(m_r - mnew);
          m_r = mnew;
          l_r *= rr;
#pragma unroll
          for (int r = 0; r < 16; ++r) { o0[r] *= rr; o1[r] *= rr; }
        }
        float sum = 0.f;
#pragma unroll
        for (int r = 0; r < 16; ++r) { s0[r] = exp2f(s0[r] - m_r); sum += s0[r]; }
#pragma unroll
        for (int r = 0; r < 16; ++r) { s1[r] = exp2f(s1[r] - m_r); sum += s1[r]; }
        sum += __shfl_xor(sum, 32);
        l_r += sum;
      }
      // PV
#pragma unroll
      for (int ksl = 0; ksl < 4; ++ksl) {
        const int b = 8 * (ksl & 1);
        const f32x16& ps = (ksl < 2) ? s0 : s1;
        u32 c0 = cvt_pk_bf16(ps[b + 0], ps[b + 1]);
        u32 c1 = cvt_pk_bf16(ps[b + 2], ps[b + 3]);
        u32 c2 = cvt_pk_bf16(ps[b + 4], ps[b + 5]);
        u32 c3 = cvt_pk_bf16(ps[b + 6], ps[b + 7]);
        pl32_swap(c0, c2);
        pl32_swap(c1, c3);
        union { u32 u[4]; short8 s; } pa;
        pa.u[0] = c0; pa.u[1] = c1; pa.u[2] = c2; pa.u[3] = c3;
        int cl = 2 * ksl + hi;
        int d0r = l & 31, d1r = (l & 31) + 32;
        short8 vf0 = *reinterpret_cast<const short8*>(&vs[d0r * 64 + ((cl ^ (d0r & 7)) * 8)]);
        short8 vf1 = *reinterpret_cast<const short8*>(&vs[d1r * 64 + ((cl ^ (d1r & 7)) * 8)]);
        o0 = __builtin_amdgcn_mfma_f32_32x32x16_bf16(vf0, pa.s, o0, 0, 0, 0);
        o1 = __builtin_amdgcn_mfma_f32_32x32x16_bf16(vf1, pa.s, o1, 0, 0, 0);
      }
    }

    // reads of this buffer done -> safe to re-stage into it after barrier
    WAIT_LGK0;
    __builtin_amdgcn_sched_barrier(0);
    __builtin_amdgcn_s_barrier();
    if (it + 3 < nst) stage(it + 3, Ksb + o0b, Vsb + o0b);
    int tmp = o0b; o0b = o1b; o1b = o2b; o2b = tmp;
  }

  // epilogue: normalize, bounce O^T -> row-major via per-wave LDS, 16B stores
  float inv = 1.0f / l_r;
  u16* Ob = smem + w * 2304;  // 32 rows x 72 u16 per wave
#pragma unroll
  for (int acc = 0; acc < 2; ++acc) {
    const f32x16& oo = acc ? o1 : o0;
#pragma unroll
    for (int rp = 0; rp < 8; ++rp) {
      u32 pk = cvt_pk_bf16(oo[2 * rp] * inv, oo[2 * rp + 1] * inv);
      int d0 = ((2 * rp) & 3) + 8 * (rp >> 1) + hi4 + 32 * acc;
      *reinterpret_cast<u32*>(&Ob[(l & 31) * 72 + d0]) = pk;
    }
  }
  __syncthreads();
  int qq = l >> 1;
  int chb = (l & 1) * 4;
#pragma unroll
  for (int c2 = 0; c2 < 4; ++c2) {
    uint4v vv = *reinterpret_cast<const uint4v*>(&Ob[qq * 72 + (chb + c2) * 8]);
    *reinterpret_cast<uint4v*>(&AO[qkbase + (size_t)(qw - w * 32 + w * 32 + qq) * D_ + (chb + c2) * 8]) = vv;
  }
}

// ---------------- launch ----------------
extern "C" void kernel_launch(void* const* d_in, const int* in_sizes, int n_in,
                              void* d_out, int out_size, void* d_ws, size_t ws_size,
                              hipStream_t stream) {
  const float* x  = (const float*)d_in[0];
  const float* wq = (const float*)d_in[1];
  const float* wk = (const float*)d_in[2];
  const float* wv = (const float*)d_in[3];
  const float* wo = (const float*)d_in[4];
  const float* bo = (const float*)d_in[5];
  float* out = (float*)d_out;

  char* ws = (char*)d_ws;
  u16* XB   = (u16*)(ws);                       // 16 MiB
  u16* WQKV = (u16*)(ws + (size_t)(16 << 20));  // 6 MiB (wq|wk|wv), then wo
  u16* WOB  = (u16*)(ws + (size_t)(22 << 20));  // 2 MiB
  u16* Qb   = (u16*)(ws + (size_t)(24 << 20));
  u16* Kb   = (u16*)(ws + (size_t)(40 << 20));
  u16* Vt   = (u16*)(ws + (size_t)(56 << 20));  // [bh*64+d][s]
  u16* AO   = (u16*)(ws + (size_t)(72 << 20));

  const int nx = B_ * S_ * D_;   // 8388608
  const int nw = D_ * D_;        // 1048576

  conv_bf16<<<nx / 2048, 256, 0, stream>>>(x, XB, nx, 1.0f);
  // wq scale folds DK^-0.5 * log2(e) for exp2-domain softmax
  conv_w4<<<dim3(nw / 2048, 4), 256, 0, stream>>>(wq, wk, wv, wo, WQKV,
                                                  0.18033688011112042f);

  gemm_bt<0><<<dim3(3072 / 128, (B_ * S_) / 128), 256, 0, stream>>>(
      XB, WQKV, Qb, Kb, Vt, nullptr, nullptr, B_ * S_, 3072, D_);

  attn_fwd<<<dim3(B_ * H_, 16), 256, 0, stream>>>(Qb, Kb, Vt, AO);

  gemm_bt<1><<<dim3(D_ / 128, (B_ * S_) / 128), 256, 0, stream>>>(
      AO, WOB, nullptr, nullptr, nullptr, out, bo, B_ * S_, D_, D_);
}